// Round 5
// baseline (347.842 us; speedup 1.0000x reference)
//
#include <hip/hip_runtime.h>
#include <hip/hip_bf16.h>
#include <stdint.h>

typedef __bf16 bf16_t;
typedef __bf16 bf16x8 __attribute__((ext_vector_type(8)));
typedef __bf16 bf16x4 __attribute__((ext_vector_type(4)));
typedef float f32x4 __attribute__((ext_vector_type(4)));

// Shapes: B=4 Ng=8192 C=256 H=W=128 Nt=512 M=8 P=4 Ch=32
#define CEXP 0.25506807186679906f  // (1/sqrt(32)) * log2(e), folded into K

__device__ __forceinline__ float ldf(const void* p, size_t i, int isf) {
  return isf ? ((const float*)p)[i] : (float)((const bf16_t*)p)[i];
}

// per-wave dtype detect on query[0:128 elems] — deterministic everywhere
__device__ __forceinline__ int detect_isf(const void* q) {
  const uint16_t* u = (const uint16_t*)q;
  const int lane = threadIdx.x & 63;
  const uint16_t v = u[2 * lane];
  const int e = (v >> 7) & 0xFF;
  const int weird = (e >= 0x86 || (v != 0 && e <= 0x65)) ? 1 : 0;
  return (__popcll(__ballot(weird)) >= 16) ? 1 : 0;
}

__device__ __forceinline__ float fexp2(float x) {
#if __has_builtin(__builtin_amdgcn_exp2f)
  return __builtin_amdgcn_exp2f(x);
#else
  return exp2f(x);
#endif
}

// 16x16x16 bf16 MFMA: C-layout of a 16x16 tile == B-layout of this shape.
__device__ __forceinline__ f32x4 mfma16x16x16(bf16x4 a, bf16x4 b, f32x4 c) {
#if __has_builtin(__builtin_amdgcn_mfma_f32_16x16x16_bf16)
  return __builtin_amdgcn_mfma_f32_16x16x16_bf16(a, b, c, 0, 0, 0);
#else
  typedef short s16x4 __attribute__((ext_vector_type(4)));
  return __builtin_amdgcn_mfma_f32_16x16x16bf16_1k(
      __builtin_bit_cast(s16x4, a), __builtin_bit_cast(s16x4, b), c, 0, 0, 0);
#endif
}

// async global->LDS, 16B per lane
__device__ __forceinline__ void stage16(const bf16_t* g, bf16_t* l) {
  __builtin_amdgcn_global_load_lds((const __attribute__((address_space(1))) void*)g,
                                   (__attribute__((address_space(3))) void*)l, 16, 0, 0);
}

// ====== merged prep: weights->bf16 blob | tf projection | wpad hi/lo =======
__global__ __launch_bounds__(256) void prep_all(
    const void* __restrict__ query,
    const void* in_w, const void* in_b, const void* mow, const void* mob,
    const void* outw, const void* outb,
    const void* trajp, const void* tw, const void* tb,
    const void* offs_w, const void* attw_w, const void* offs_b, const void* attw_b,
    bf16_t* __restrict__ blob, bf16_t* __restrict__ tf,
    bf16_t* __restrict__ Wph, bf16_t* __restrict__ Wpl, bf16_t* __restrict__ bp)
{
  const int isf = detect_isf(query);
  const int bid = blockIdx.x;
  if (bid < 322) {
    const int g = (bid * 256 + threadIdx.x) * 4;
    if (g >= 328960) return;
    const void* src; size_t off;
    if      (g < 196608) { src = in_w; off = g; }
    else if (g < 197376) { src = in_b; off = g - 196608; }
    else if (g < 262912) { src = mow;  off = g - 197376; }
    else if (g < 263168) { src = mob;  off = g - 262912; }
    else if (g < 328704) { src = outw; off = g - 263168; }
    else                 { src = outb; off = g - 328704; }
#pragma unroll
    for (int k = 0; k < 4; k++) blob[g + k] = (bf16_t)ldf(src, off + k, isf);
  } else if (bid < 322 + 2048) {
    const int rowb = bid - 322;
    const int c = threadIdx.x;
    const float x = ldf(trajp, rowb * 2 + 0, isf);
    const float y = ldf(trajp, rowb * 2 + 1, isf);
    const float v = x * ldf(tw, c * 2 + 0, isf) + y * ldf(tw, c * 2 + 1, isf) + ldf(tb, c, isf);
    tf[(size_t)rowb * 256 + c] = (bf16_t)v;
  } else {
    const int idx = (bid - 2370) * 256 + threadIdx.x;
    const int rowp = idx >> 8, c = idx & 255;
    float v = 0.0f;
    if (rowp < 64)      v = ldf(offs_w, rowp * 256 + c, isf);
    else if (rowp < 96) v = ldf(attw_w, (rowp - 64) * 256 + c, isf);
    const bf16_t hi = (bf16_t)v;
    Wph[idx] = hi;
    Wpl[idx] = (bf16_t)(v - (float)hi);
    if (idx < 128) {
      float bv = 0.0f;
      if (idx < 64)      bv = ldf(offs_b, idx, isf);
      else if (idx < 96) bv = ldf(attw_b, idx - 64, isf);
      bp[idx] = (bf16_t)bv;
    }
  }
}

// ============== async-staged bf16 GEMM: C = A@W^T + bias ===================
// mode 0: bf16 store; mode 3: dtype-of-query store; mode 6: K scaled + V transposed
#define TM 128
#define TN 128
#define TKK 64

__global__ __launch_bounds__(256) void gemm_async(
    const bf16_t* __restrict__ A, const bf16_t* __restrict__ W,
    const bf16_t* __restrict__ bias, void* __restrict__ Cout,
    void* __restrict__ Cout2, int Ndim, int Kdim, int mode, float kscale,
    const void* __restrict__ qdet)
{
  __shared__ __align__(16) bf16_t As[TM * TKK];
  __shared__ __align__(16) bf16_t Ws[TN * TKK];
  const int t    = threadIdx.x;
  const int lane = t & 63;
  const int w    = t >> 6;
  const int wm   = (w & 1) * 64;
  const int wn   = (w >> 1) * 64;
  const int q4   = lane >> 4;
  const int r16  = lane & 15;
  const int tm   = blockIdx.x * TM;
  const int tn   = blockIdx.y * TN;

  f32x4 acc[4][4] = {};

  for (int kt = 0; kt < Kdim; kt += TKK) {
    __syncthreads();
#pragma unroll
    for (int r = 0; r < 4; r++) {
      const int L = w * 256 + r * 64 + lane;
      const int R = L >> 3, c = (L & 7) * 8;
      stage16(A + (size_t)(tm + R) * Kdim + kt + c, As + L * 8);
      stage16(W + (size_t)(tn + R) * Kdim + kt + c, Ws + L * 8);
    }
    __syncthreads();
#pragma unroll
    for (int ks = 0; ks < TKK; ks += 32) {
      bf16x8 af[4], bfm[4];
#pragma unroll
      for (int i = 0; i < 4; i++)
        af[i] = *(const bf16x8*)(As + (wm + 16 * i + r16) * TKK + ks + q4 * 8);
#pragma unroll
      for (int j = 0; j < 4; j++)
        bfm[j] = *(const bf16x8*)(Ws + (wn + 16 * j + r16) * TKK + ks + q4 * 8);
#pragma unroll
      for (int i = 0; i < 4; i++)
#pragma unroll
        for (int j = 0; j < 4; j++)
          acc[i][j] = __builtin_amdgcn_mfma_f32_16x16x32_bf16(af[i], bfm[j], acc[i][j], 0, 0, 0);
    }
  }

  const int isf = (mode == 3) ? detect_isf(qdet) : 1;
#pragma unroll
  for (int j = 0; j < 4; j++) {
    const int col = tn + wn + 16 * j + r16;
    const float bv = (float)bias[col];
#pragma unroll
    for (int i = 0; i < 4; i++) {
      const int row0 = tm + wm + 16 * i + q4 * 4;
#pragma unroll
      for (int rr = 0; rr < 4; rr++) {
        const float v = acc[i][j][rr] + bv;
        const size_t off = (size_t)(row0 + rr) * Ndim + col;
        if (mode == 0) {
          ((bf16_t*)Cout)[off] = (bf16_t)v;
        } else if (mode == 6) {
          const int rowg = row0 + rr;
          if (col < 256) {
            ((bf16_t*)Cout)[(size_t)rowg * 256 + col] = (bf16_t)(v * kscale);
          } else {
            const int bb = rowg >> 9, tt = rowg & 511;
            const int c2 = col - 256;
            const int mm = c2 >> 5, ch = c2 & 31;
            ((bf16_t*)Cout2)[(((size_t)(bb * 8 + mm) * 32 + ch) << 9) + tt] = (bf16_t)v;
          }
        } else {
          if (isf) ((float*)Cout)[off] = v; else ((bf16_t*)Cout)[off] = (bf16_t)v;
        }
      }
    }
  }
}

// ============== VGPR-staged GEMM with dtype-flex A (Q-proj) ================
__global__ __launch_bounds__(256) void gemm_f32a(
    const void* __restrict__ Araw, const bf16_t* __restrict__ W,
    const bf16_t* __restrict__ bias, bf16_t* __restrict__ Cout,
    int Ndim, int Kdim, const void* __restrict__ qdet)
{
  __shared__ __align__(16) bf16_t As[TM * TKK];
  __shared__ __align__(16) bf16_t Ws[TN * TKK];
  const int t    = threadIdx.x;
  const int lane = t & 63;
  const int w    = t >> 6;
  const int wm   = (w & 1) * 64;
  const int wn   = (w >> 1) * 64;
  const int q4   = lane >> 4;
  const int r16  = lane & 15;
  const int tm   = blockIdx.x * TM;
  const int tn   = blockIdx.y * TN;
  const int aisf = detect_isf(qdet);

  f32x4 acc[4][4] = {};
  const int srow = t >> 1;
  const int skb  = (t & 1) * 32;

  for (int kt = 0; kt < Kdim; kt += TKK) {
    __syncthreads();
    if (aisf) {
      const float4* ga = (const float4*)((const float*)Araw + (size_t)(tm + srow) * Kdim + kt + skb);
#pragma unroll
      for (int kk = 0; kk < 8; kk++) {
        const float4 u = ga[kk];
        bf16x4 h = {(bf16_t)u.x, (bf16_t)u.y, (bf16_t)u.z, (bf16_t)u.w};
        *(bf16x4*)(As + srow * TKK + skb + kk * 4) = h;
      }
    } else {
      const uint4* ga = (const uint4*)((const bf16_t*)Araw + (size_t)(tm + srow) * Kdim + kt + skb);
      uint4* la = (uint4*)(As + srow * TKK + skb);
      la[0] = ga[0]; la[1] = ga[1]; la[2] = ga[2]; la[3] = ga[3];
    }
    {
      const uint4* gw = (const uint4*)(W + (size_t)(tn + srow) * Kdim + kt + skb);
      uint4* lw = (uint4*)(Ws + srow * TKK + skb);
      lw[0] = gw[0]; lw[1] = gw[1]; lw[2] = gw[2]; lw[3] = gw[3];
    }
    __syncthreads();
#pragma unroll
    for (int ks = 0; ks < TKK; ks += 32) {
      bf16x8 af[4], bfm[4];
#pragma unroll
      for (int i = 0; i < 4; i++)
        af[i] = *(const bf16x8*)(As + (wm + 16 * i + r16) * TKK + ks + q4 * 8);
#pragma unroll
      for (int j = 0; j < 4; j++)
        bfm[j] = *(const bf16x8*)(Ws + (wn + 16 * j + r16) * TKK + ks + q4 * 8);
#pragma unroll
      for (int i = 0; i < 4; i++)
#pragma unroll
        for (int j = 0; j < 4; j++)
          acc[i][j] = __builtin_amdgcn_mfma_f32_16x16x32_bf16(af[i], bfm[j], acc[i][j], 0, 0, 0);
    }
  }

#pragma unroll
  for (int j = 0; j < 4; j++) {
    const int col = tn + wn + 16 * j + r16;
    const float bv = (float)bias[col];
#pragma unroll
    for (int i = 0; i < 4; i++) {
      const int row0 = tm + wm + 16 * i + q4 * 4;
#pragma unroll
      for (int rr = 0; rr < 4; rr++)
        Cout[(size_t)(row0 + rr) * Ndim + col] = (bf16_t)(acc[i][j][rr] + bv);
    }
  }
}

// ==================== attention: LDS-free, per-head ========================
// K pre-scaled by CEXP. S^T = K·Q^T; p = exp2(s); O^T = V^T·P^T.
// grid (Ng/512, B*M); wave owns 128 q-rows (8 q-tiles) -> 8 independent
// MFMA->exp2->MFMA chains per K-tile (ILP) + 8x arithmetic per K/V load.
// Prefetch depth 2 (named A/B register sets — no runtime indexing) covers
// ~2x L2 latency; setprio(1) around compute favors in-compute waves
// (barrier-free kernel, waves drift out of phase — the m191 regime).
__global__ __launch_bounds__(256, 2) void attn_kernel(
    const bf16_t* __restrict__ Q, const bf16_t* __restrict__ Kk,
    const bf16_t* __restrict__ Vt, bf16_t* __restrict__ ctx)
{
  const int t = threadIdx.x;
  const int lane = t & 63, w = t >> 6;
  const int q4 = lane >> 4, r16 = lane & 15;
  const int bm = blockIdx.y;
  const int b = bm >> 3, m = bm & 7;
  const int q0 = blockIdx.x * 512 + w * 128;

  bf16x8 qf[8];
#pragma unroll
  for (int qt = 0; qt < 8; qt++)
    qf[qt] = *(const bf16x8*)(Q + ((size_t)(b * 8192 + q0 + qt * 16 + r16) * 256 + m * 32 + q4 * 8));

  f32x4 acc[8][2] = {};
  float lsum[8] = {0.f, 0.f, 0.f, 0.f, 0.f, 0.f, 0.f, 0.f};

  const bf16_t* kbase  = Kk + (size_t)b * 512 * 256 + m * 32 + (size_t)r16 * 256 + q4 * 8;
  const bf16_t* vbase0 = Vt + (size_t)bm * 32 * 512 + ((size_t)r16 << 9) + q4 * 4;
  const bf16_t* vbase1 = vbase0 + (16 << 9);

  // prefetch slots A (k0) and B (k0+16); over-reads past k=512 land in the
  // adjacent allocated ws regions (vt_g/blob) and are never consumed — safe.
  bf16x8 kfA = *(const bf16x8*)(kbase);
  bf16x4 v0A = *(const bf16x4*)(vbase0);
  bf16x4 v1A = *(const bf16x4*)(vbase1);
  bf16x8 kfB = *(const bf16x8*)(kbase + (size_t)16 * 256);
  bf16x4 v0B = *(const bf16x4*)(vbase0 + 16);
  bf16x4 v1B = *(const bf16x4*)(vbase1 + 16);

  for (int k0 = 0; k0 < 512; k0 += 32) {
    // ---- tile k0 from slot A; prefetch k0+32 into A ----
    const bf16x8 ka = kfA;
    const bf16x4 va0 = v0A, va1 = v1A;
    kfA = *(const bf16x8*)(kbase + (size_t)(k0 + 32) * 256);
    v0A = *(const bf16x4*)(vbase0 + k0 + 32);
    v1A = *(const bf16x4*)(vbase1 + k0 + 32);
    __builtin_amdgcn_s_setprio(1);
#pragma unroll
    for (int qt = 0; qt < 8; qt++) {
      f32x4 z = {};
      const f32x4 s = __builtin_amdgcn_mfma_f32_16x16x32_bf16(ka, qf[qt], z, 0, 0, 0);
      const float e0 = fexp2(s[0]), e1 = fexp2(s[1]);
      const float e2 = fexp2(s[2]), e3 = fexp2(s[3]);
      lsum[qt] += (e0 + e1) + (e2 + e3);
      // compiler pairs these casts into v_cvt_pk_bf16_f32 (m240)
      const bf16x4 p = {(bf16_t)e0, (bf16_t)e1, (bf16_t)e2, (bf16_t)e3};
      acc[qt][0] = mfma16x16x16(va0, p, acc[qt][0]);
      acc[qt][1] = mfma16x16x16(va1, p, acc[qt][1]);
    }
    __builtin_amdgcn_s_setprio(0);
    // ---- tile k0+16 from slot B; prefetch k0+48 into B ----
    const bf16x8 kb = kfB;
    const bf16x4 vb0 = v0B, vb1 = v1B;
    kfB = *(const bf16x8*)(kbase + (size_t)(k0 + 48) * 256);
    v0B = *(const bf16x4*)(vbase0 + k0 + 48);
    v1B = *(const bf16x4*)(vbase1 + k0 + 48);
    __builtin_amdgcn_s_setprio(1);
#pragma unroll
    for (int qt = 0; qt < 8; qt++) {
      f32x4 z = {};
      const f32x4 s = __builtin_amdgcn_mfma_f32_16x16x32_bf16(kb, qf[qt], z, 0, 0, 0);
      const float e0 = fexp2(s[0]), e1 = fexp2(s[1]);
      const float e2 = fexp2(s[2]), e3 = fexp2(s[3]);
      lsum[qt] += (e0 + e1) + (e2 + e3);
      const bf16x4 p = {(bf16_t)e0, (bf16_t)e1, (bf16_t)e2, (bf16_t)e3};
      acc[qt][0] = mfma16x16x16(vb0, p, acc[qt][0]);
      acc[qt][1] = mfma16x16x16(vb1, p, acc[qt][1]);
    }
    __builtin_amdgcn_s_setprio(0);
  }

#pragma unroll
  for (int qt = 0; qt < 8; qt++) {
    float v = lsum[qt];
    v += __shfl_xor(v, 16, 64);
    v += __shfl_xor(v, 32, 64);
    const float inv = 1.0f / v;
    const size_t row = (size_t)b * 8192 + q0 + qt * 16 + r16;
    bf16x4 o0, o1;
#pragma unroll
    for (int rr = 0; rr < 4; rr++) {
      o0[rr] = (bf16_t)(acc[qt][0][rr] * inv);
      o1[rr] = (bf16_t)(acc[qt][1][rr] * inv);
    }
    *(bf16x4*)(ctx + row * 256 + m * 32 + q4 * 4)      = o0;
    *(bf16x4*)(ctx + row * 256 + m * 32 + 16 + q4 * 4) = o1;
  }
}

// ================= residual + LayerNorm -> gq hi/lo split ==================
// lane owns 4 CONTIGUOUS columns -> float4/bf16x4 vector loads+stores
__global__ __launch_bounds__(256) void ln_kernel(
    const bf16_t* __restrict__ y2, const void* __restrict__ query,
    const void* __restrict__ g, const void* __restrict__ beta,
    bf16_t* __restrict__ gqh, bf16_t* __restrict__ gql)
{
  const int isf = detect_isf(query);
  const int rowb = blockIdx.x * 4 + (threadIdx.x >> 6);
  const int lane = threadIdx.x & 63;
  const size_t base = (size_t)rowb * 256;
  const int c0 = lane * 4;
  float x[4];
  {
    const bf16x4 yv = *(const bf16x4*)(y2 + base + c0);
    if (isf) {
      const float4 qv = *(const float4*)((const float*)query + base + c0);
      x[0] = qv.x + (float)yv[0]; x[1] = qv.y + (float)yv[1];
      x[2] = qv.z + (float)yv[2]; x[3] = qv.w + (float)yv[3];
    } else {
      const bf16x4 qv = *(const bf16x4*)((const bf16_t*)query + base + c0);
#pragma unroll
      for (int k = 0; k < 4; k++) x[k] = (float)qv[k] + (float)yv[k];
    }
  }
  float s = x[0] + x[1] + x[2] + x[3];
  for (int d = 1; d < 64; d <<= 1) s += __shfl_xor(s, d, 64);
  const float mu = s * (1.0f / 256.0f);
  float vs = 0.f;
#pragma unroll
  for (int k = 0; k < 4; k++) { const float d = x[k] - mu; vs += d * d; }
  for (int d = 1; d < 64; d <<= 1) vs += __shfl_xor(vs, d, 64);
  const float rstd = rsqrtf(vs * (1.0f / 256.0f) + 1e-5f);
  float gw[4], bb[4];
  if (isf) {
    const float4 gg = *(const float4*)((const float*)g + c0);
    const float4 bv = *(const float4*)((const float*)beta + c0);
    gw[0] = gg.x; gw[1] = gg.y; gw[2] = gg.z; gw[3] = gg.w;
    bb[0] = bv.x; bb[1] = bv.y; bb[2] = bv.z; bb[3] = bv.w;
  } else {
    const bf16x4 gg = *(const bf16x4*)((const bf16_t*)g + c0);
    const bf16x4 bv = *(const bf16x4*)((const bf16_t*)beta + c0);
#pragma unroll
    for (int k = 0; k < 4; k++) { gw[k] = (float)gg[k]; bb[k] = (float)bv[k]; }
  }
  bf16x4 hi4, lo4;
#pragma unroll
  for (int k = 0; k < 4; k++) {
    const float gv = (x[k] - mu) * rstd * gw[k] + bb[k];
    const bf16_t hi = (bf16_t)gv;
    hi4[k] = hi;
    lo4[k] = (bf16_t)(gv - (float)hi);
  }
  *(bf16x4*)(gqh + base + c0) = hi4;
  *(bf16x4*)(gql + base + c0) = lo4;
}

// ===== fused offs/attw GEMM: ysamp = gqh*(Wh+Wl)^T + gql*Wh^T + bias =======
__global__ __launch_bounds__(256) void gemm_offs(
    const bf16_t* __restrict__ Ahg, const bf16_t* __restrict__ Alg,
    const bf16_t* __restrict__ Whg, const bf16_t* __restrict__ Wlg,
    const bf16_t* __restrict__ bias, float* __restrict__ Cout)
{
  __shared__ __align__(16) bf16_t Ah[128 * 64];
  __shared__ __align__(16) bf16_t Al[128 * 64];
  __shared__ __align__(16) bf16_t Wh[128 * 64];
  __shared__ __align__(16) bf16_t Wl[128 * 64];
  const int t    = threadIdx.x;
  const int lane = t & 63;
  const int w    = t >> 6;
  const int wm   = (w & 1) * 64;
  const int wn   = (w >> 1) * 64;
  const int q4   = lane >> 4;
  const int r16  = lane & 15;
  const int tm   = blockIdx.x * 128;

  f32x4 acc[4][4] = {};
  const int srow = t >> 1;
  const int skb  = (t & 1) * 32;

  for (int kt = 0; kt < 256; kt += 64) {
    __syncthreads();
    {
      const uint4* g0 = (const uint4*)(Ahg + (size_t)(tm + srow) * 256 + kt + skb);
      uint4* l0 = (uint4*)(Ah + srow * 64 + skb);
      l0[0] = g0[0]; l0[1] = g0[1]; l0[2] = g0[2]; l0[3] = g0[3];
      const uint4* g1 = (const uint4*)(Alg + (size_t)(tm + srow) * 256 + kt + skb);
      uint4* l1 = (uint4*)(Al + srow * 64 + skb);
      l1[0] = g1[0]; l1[1] = g1[1]; l1[2] = g1[2]; l1[3] = g1[3];
      const uint4* g2 = (const uint4*)(Whg + (size_t)srow * 256 + kt + skb);
      uint4* l2 = (uint4*)(Wh + srow * 64 + skb);
      l2[0] = g2[0]; l2[1] = g2[1]; l2[2] = g2[2]; l2[3] = g2[3];
      const uint4* g3 = (const uint4*)(Wlg + (size_t)srow * 256 + kt + skb);
      uint4* l3 = (uint4*)(Wl + srow * 64 + skb);
      l3[0] = g3[0]; l3[1] = g3[1]; l3[2] = g3[2]; l3[3] = g3[3];
    }
    __syncthreads();
#pragma unroll
    for (int ks = 0; ks < 64; ks += 32) {
      bf16x8 ah[4], al[4], bh[4], bl[4];
#pragma unroll
      for (int i = 0; i < 4; i++) {
        ah[i] = *(const bf16x8*)(Ah + (wm + 16 * i + r16) * 64 + ks + q4 * 8);
        al[i] = *(const bf16x8*)(Al + (wm + 16 * i + r16) * 64 + ks + q4 * 8);
      }
#pragma unroll
      for (int j = 0; j < 4; j++) {
        bh[j] = *(const bf16x8*)(Wh + (wn + 16 * j + r16) * 64 + ks + q4 * 8);
        bl[j] = *(const bf16x8*)(Wl + (wn + 16 * j + r16) * 64 + ks + q4 * 8);
      }
#pragma unroll
      for (int i = 0; i < 4; i++)
#pragma unroll
        for (int j = 0; j < 4; j++) {
          f32x4 a = acc[i][j];
          a = __builtin_amdgcn_mfma_f32_16x16x32_bf16(al[i], bh[j], a, 0, 0, 0);
          a = __builtin_amdgcn_mfma_f32_16x16x32_bf16(ah[i], bl[j], a, 0, 0, 0);
          a = __builtin_amdgcn_mfma_f32_16x16x32_bf16(ah[i], bh[j], a, 0, 0, 0);
          acc[i][j] = a;
        }
    }
  }

#pragma unroll
  for (int j = 0; j < 4; j++) {
    const int col = wn + 16 * j + r16;
    const float bv = (float)bias[col];
#pragma unroll
    for (int i = 0; i < 4; i++) {
      const int row0 = tm + wm + 16 * i + q4 * 4;
#pragma unroll
      for (int rr = 0; rr < 4; rr++)
        Cout[(size_t)(row0 + rr) * 128 + col] = acc[i][j][rr] + bv;
    }
  }
}

// ============ value transpose (B,C,H,W) -> (B,M,H,W,Ch) bf16 ===============
// vectorized: 16-32B global loads, ds_write_b128 into [ch][ww] tile,
// scalar LDS gather (<=4-way), bf16x8 global stores (2KB contiguous/wave)
__global__ __launch_bounds__(256) void transpose_value(
    const void* __restrict__ V, bf16_t* __restrict__ Vp, const void* __restrict__ qdet)
{
  __shared__ __align__(16) bf16_t tile[32][136];
  const int isf = detect_isf(qdet);
  const int bid = blockIdx.x;
  const int h = bid & 127;
  const int bm = bid >> 7;
  const int b = bm >> 3, mm = bm & 7;
  const int t = threadIdx.x;
  // load: thread owns (ch = t>>3, ww0 = (t&7)*16) -> 16 contiguous ww
  const int ch  = t >> 3;
  const int ww0 = (t & 7) * 16;
  const size_t ibase = (((size_t)b * 256 + mm * 32 + ch) * 128 + h) * 128 + ww0;
  if (isf) {
    const float4* src = (const float4*)((const float*)V + ibase);
    bf16x8 h0, h1;
#pragma unroll
    for (int k = 0; k < 2; k++) {
      const float4 u0 = src[k * 2], u1 = src[k * 2 + 1];
      bf16x8 hh = {(bf16_t)u0.x, (bf16_t)u0.y, (bf16_t)u0.z, (bf16_t)u0.w,
                   (bf16_t)u1.x, (bf16_t)u1.y, (bf16_t)u1.z, (bf16_t)u1.w};
      if (k == 0) h0 = hh; else h1 = hh;
    }
    *(bf16x8*)(&tile[ch][ww0])     = h0;
    *(bf16x8*)(&tile[ch][ww0 + 8]) = h1;
  } else {
    const bf16x8* src = (const bf16x8*)((const bf16_t*)V + ibase);
    *(bf16x8*)(&tile[ch][ww0])     = src[0];
    *(bf16x8*)(&tile[ch][ww0 + 8]) = src[1];
  }
  __syncthreads();
  // store: thread owns (ww = t>>1, c0 = (t&1)*16) -> 32 contiguous ch out
  const size_t base = ((size_t)bm * 128 + h) * 4096;
  const int ww = t >> 1;
  const int c0 = (t & 1) * 16;
  bf16x8 o0, o1;
#pragma unroll
  for (int e = 0; e < 8; e++) { o0[e] = tile[c0 + e][ww]; o1[e] = tile[c0 + 8 + e][ww]; }
  *(bf16x8*)(Vp + base + ww * 32 + c0)     = o0;
  *(bf16x8*)(Vp + base + ww * 32 + c0 + 8) = o1;
}

// ===================== deformable bilinear sampler =========================
// R2-proven divergent body (VGPR 44) + R3-proven 1D sequential-slice swizzle:
// bm = (wg&7) + 8*(wg>>8), qt = (wg>>3)&31. Consecutive 256 blocks cover only
// bm 0..7 -> each XCD streams ONE 1MB vperm slice at a time (sequential slice
// residency, FETCH 50MB in R3). R4's transpose (4 slices/XCD live) thrashed.
__global__ __launch_bounds__(256) void sampler(
    const float* __restrict__ ys, const void* __restrict__ refp,
    const bf16_t* __restrict__ vperm, bf16_t* __restrict__ outs,
    const void* __restrict__ qdet)
{
  const int isf = detect_isf(qdet);
  const int t = threadIdx.x;
  const int wg = blockIdx.x;
  const int bm = (wg & 7) + ((wg >> 8) << 3);   // XCD = wg%8 = bm%8, sequential slices
  const int qt = (wg >> 3) & 31;
  const int b = bm >> 3, m = bm & 7;
  const int qq = qt * 256 + t;
  const size_t row = (size_t)b * 8192 + qq;
  const float* y = ys + row * 128;
  const float rx = ldf(refp, row * 2 + 0, isf);
  const float ry = ldf(refp, row * 2 + 1, isf);

  const float l0 = y[64 + m * 4 + 0], l1 = y[64 + m * 4 + 1];
  const float l2 = y[64 + m * 4 + 2], l3 = y[64 + m * 4 + 3];
  const float mx = fmaxf(fmaxf(l0, l1), fmaxf(l2, l3));
  const float e0 = __expf(l0 - mx), e1 = __expf(l1 - mx);
  const float e2 = __expf(l2 - mx), e3 = __expf(l3 - mx);
  const float inv = 1.0f / (e0 + e1 + e2 + e3);
  const float aw[4] = {e0 * inv, e1 * inv, e2 * inv, e3 * inv};

  float acc[32];
#pragma unroll
  for (int ch = 0; ch < 32; ch++) acc[ch] = 0.0f;

  const bf16_t* vbase = vperm + (size_t)bm * (128 * 128 * 32);

  for (int p = 0; p < 4; p++) {
    const float gx = (rx + y[m * 8 + p * 2 + 0]) * 128.0f - 0.5f;
    const float gy = (ry + y[m * 8 + p * 2 + 1]) * 128.0f - 0.5f;
    const float x0f = floorf(gx), y0f = floorf(gy);
    const int x0 = (int)x0f, y0i = (int)y0f;
    const float wx1 = gx - x0f, wx0 = 1.0f - wx1;
    const float wy1 = gy - y0f, wy0 = 1.0f - wy1;
    const float a = aw[p];
    for (int cy = 0; cy < 2; cy++) {
      const int yy = y0i + cy;
      if (yy < 0 || yy >= 128) continue;
      const float wy = cy ? wy1 : wy0;
      for (int cx = 0; cx < 2; cx++) {
        const int xx = x0 + cx;
        if (xx < 0 || xx >= 128) continue;
        const float wgt = a * wy * (cx ? wx1 : wx0);
        const bf16x8* src8 = (const bf16x8*)(vbase + ((size_t)yy * 128 + xx) * 32);
#pragma unroll
        for (int vv = 0; vv < 4; vv++) {
          const bf16x8 d = src8[vv];
#pragma unroll
          for (int e = 0; e < 8; e++) acc[vv * 8 + e] += wgt * (float)d[e];
        }
      }
    }
  }

  const size_t obase = (size_t)b * 8192;
#pragma unroll
  for (int ch = 0; ch < 32; ch++) {
    const size_t orow = obase + (size_t)(ch * 8 + m) * 32 + qt;
    outs[orow * 256 + t] = (bf16_t)acc[ch];
  }
}

// ===========================================================================
extern "C" void kernel_launch(void* const* d_in, const int* in_sizes, int n_in,
                              void* d_out, int out_size, void* d_ws, size_t ws_size,
                              hipStream_t stream) {
  const void* query = d_in[0];
  const void* value = d_in[1];
  const void* refp  = d_in[2];
  const void* trajp = d_in[3];
  const void* in_w  = d_in[4];
  const void* in_b  = d_in[5];
  const void* mow   = d_in[6];
  const void* mob   = d_in[7];
  const void* lng   = d_in[8];
  const void* lnb   = d_in[9];
  const void* tw    = d_in[10];
  const void* tb    = d_in[11];
  const void* ow    = d_in[12];
  const void* ob    = d_in[13];
  const void* aww   = d_in[14];
  const void* awb   = d_in[15];
  const void* outw  = d_in[16];
  const void* outb  = d_in[17];

  char* base = (char*)d_ws;
  float*  ysamp = (float*)(base);
  bf16_t* qout  = (bf16_t*)(base + 16777216);
  bf16_t* ctx   = (bf16_t*)(base + 33554432);
  bf16_t* y2    = (bf16_t*)(base + 50331648);
  bf16_t* tf_ws = (bf16_t*)(base + 67108864);
  bf16_t* k_ws  = (bf16_t*)(base + 68157440);
  bf16_t* vt_g  = (bf16_t*)(base + 69206016);
  bf16_t* blob  = (bf16_t*)(base + 70254592);

  bf16_t* gqh   = qout;
  bf16_t* gql   = ctx;
  bf16_t* vperm = (bf16_t*)(base + 16777216);   // 32MB, alias R1+R2
  bf16_t* outs  = y2;

  bf16_t* inw_bf  = blob;
  bf16_t* inb_bf  = blob + 196608;
  bf16_t* mow_bf  = blob + 197376;
  bf16_t* mob_bf  = blob + 262912;
  bf16_t* outw_bf = blob + 263168;
  bf16_t* outb_bf = blob + 328704;
  bf16_t* wph     = blob + 328960;
  bf16_t* wpl     = blob + 361728;
  bf16_t* bpad    = blob + 394496;

  prep_all<<<dim3(2498), dim3(256), 0, stream>>>(
      query, in_w, in_b, mow, mob, outw, outb, trajp, tw, tb,
      ow, aww, ob, awb, blob, tf_ws, wph, wpl, bpad);
  gemm_async<<<dim3(16, 4), dim3(256), 0, stream>>>(
      tf_ws, inw_bf + 65536, inb_bf + 256, (void*)k_ws, (void*)vt_g, 512, 256, 6, CEXP, query);
  gemm_f32a<<<dim3(256, 2), dim3(256), 0, stream>>>(
      query, inw_bf, inb_bf, qout, 256, 256, query);
  attn_kernel<<<dim3(16, 32), dim3(256), 0, stream>>>(qout, k_ws, vt_g, ctx);
  gemm_async<<<dim3(256, 2), dim3(256), 0, stream>>>(
      ctx, mow_bf, mob_bf, (void*)y2, nullptr, 256, 256, 0, 1.0f, query);
  ln_kernel<<<dim3(8192), dim3(256), 0, stream>>>(y2, query, lng, lnb, gqh, gql);
  gemm_offs<<<dim3(256, 1), dim3(256), 0, stream>>>(gqh, gql, wph, wpl, bpad, ysamp);
  transpose_value<<<dim3(4096), dim3(256), 0, stream>>>(value, vperm, query);
  sampler<<<dim3(1024), dim3(256), 0, stream>>>(ysamp, refp, vperm, outs, query);
  gemm_async<<<dim3(256, 2), dim3(256), 0, stream>>>(
      outs, outw_bf, outb_bf, d_out, nullptr, 256, 256, 3, 1.0f, query);
}

// Round 6
// 336.276 us; speedup vs baseline: 1.0344x; 1.0344x over previous
//
#include <hip/hip_runtime.h>
#include <hip/hip_bf16.h>
#include <stdint.h>

typedef __bf16 bf16_t;
typedef __bf16 bf16x8 __attribute__((ext_vector_type(8)));
typedef __bf16 bf16x4 __attribute__((ext_vector_type(4)));
typedef float f32x4 __attribute__((ext_vector_type(4)));

// Shapes: B=4 Ng=8192 C=256 H=W=128 Nt=512 M=8 P=4 Ch=32
#define CEXP 0.25506807186679906f  // (1/sqrt(32)) * log2(e), folded into K

__device__ __forceinline__ float ldf(const void* p, size_t i, int isf) {
  return isf ? ((const float*)p)[i] : (float)((const bf16_t*)p)[i];
}

// per-wave dtype detect on query[0:128 elems] — deterministic everywhere
__device__ __forceinline__ int detect_isf(const void* q) {
  const uint16_t* u = (const uint16_t*)q;
  const int lane = threadIdx.x & 63;
  const uint16_t v = u[2 * lane];
  const int e = (v >> 7) & 0xFF;
  const int weird = (e >= 0x86 || (v != 0 && e <= 0x65)) ? 1 : 0;
  return (__popcll(__ballot(weird)) >= 16) ? 1 : 0;
}

__device__ __forceinline__ float fexp2(float x) {
#if __has_builtin(__builtin_amdgcn_exp2f)
  return __builtin_amdgcn_exp2f(x);
#else
  return exp2f(x);
#endif
}

// 16x16x16 bf16 MFMA: C-layout of a 16x16 tile == B-layout of this shape.
__device__ __forceinline__ f32x4 mfma16x16x16(bf16x4 a, bf16x4 b, f32x4 c) {
#if __has_builtin(__builtin_amdgcn_mfma_f32_16x16x16_bf16)
  return __builtin_amdgcn_mfma_f32_16x16x16_bf16(a, b, c, 0, 0, 0);
#else
  typedef short s16x4 __attribute__((ext_vector_type(4)));
  return __builtin_amdgcn_mfma_f32_16x16x16bf16_1k(
      __builtin_bit_cast(s16x4, a), __builtin_bit_cast(s16x4, b), c, 0, 0, 0);
#endif
}

// async global->LDS, 16B per lane
__device__ __forceinline__ void stage16(const bf16_t* g, bf16_t* l) {
  __builtin_amdgcn_global_load_lds((const __attribute__((address_space(1))) void*)g,
                                   (__attribute__((address_space(3))) void*)l, 16, 0, 0);
}

// ====== merged prep: weights->bf16 blob | tf projection | wpad hi/lo =======
__global__ __launch_bounds__(256) void prep_all(
    const void* __restrict__ query,
    const void* in_w, const void* in_b, const void* mow, const void* mob,
    const void* outw, const void* outb,
    const void* trajp, const void* tw, const void* tb,
    const void* offs_w, const void* attw_w, const void* offs_b, const void* attw_b,
    bf16_t* __restrict__ blob, bf16_t* __restrict__ tf,
    bf16_t* __restrict__ Wph, bf16_t* __restrict__ Wpl, bf16_t* __restrict__ bp)
{
  const int isf = detect_isf(query);
  const int bid = blockIdx.x;
  if (bid < 322) {
    const int g = (bid * 256 + threadIdx.x) * 4;
    if (g >= 328960) return;
    const void* src; size_t off;
    if      (g < 196608) { src = in_w; off = g; }
    else if (g < 197376) { src = in_b; off = g - 196608; }
    else if (g < 262912) { src = mow;  off = g - 197376; }
    else if (g < 263168) { src = mob;  off = g - 262912; }
    else if (g < 328704) { src = outw; off = g - 263168; }
    else                 { src = outb; off = g - 328704; }
#pragma unroll
    for (int k = 0; k < 4; k++) blob[g + k] = (bf16_t)ldf(src, off + k, isf);
  } else if (bid < 322 + 2048) {
    const int rowb = bid - 322;
    const int c = threadIdx.x;
    const float x = ldf(trajp, rowb * 2 + 0, isf);
    const float y = ldf(trajp, rowb * 2 + 1, isf);
    const float v = x * ldf(tw, c * 2 + 0, isf) + y * ldf(tw, c * 2 + 1, isf) + ldf(tb, c, isf);
    tf[(size_t)rowb * 256 + c] = (bf16_t)v;
  } else {
    const int idx = (bid - 2370) * 256 + threadIdx.x;
    const int rowp = idx >> 8, c = idx & 255;
    float v = 0.0f;
    if (rowp < 64)      v = ldf(offs_w, rowp * 256 + c, isf);
    else if (rowp < 96) v = ldf(attw_w, (rowp - 64) * 256 + c, isf);
    const bf16_t hi = (bf16_t)v;
    Wph[idx] = hi;
    Wpl[idx] = (bf16_t)(v - (float)hi);
    if (idx < 128) {
      float bv = 0.0f;
      if (idx < 64)      bv = ldf(offs_b, idx, isf);
      else if (idx < 96) bv = ldf(attw_b, idx - 64, isf);
      bp[idx] = (bf16_t)bv;
    }
  }
}

// ============== async-staged bf16 GEMM: C = A@W^T + bias ===================
// mode 0: bf16 store; mode 3: dtype-of-query store; mode 6: K scaled + V transposed
#define TM 128
#define TN 128
#define TKK 64

__global__ __launch_bounds__(256) void gemm_async(
    const bf16_t* __restrict__ A, const bf16_t* __restrict__ W,
    const bf16_t* __restrict__ bias, void* __restrict__ Cout,
    void* __restrict__ Cout2, int Ndim, int Kdim, int mode, float kscale,
    const void* __restrict__ qdet)
{
  __shared__ __align__(16) bf16_t As[TM * TKK];
  __shared__ __align__(16) bf16_t Ws[TN * TKK];
  const int t    = threadIdx.x;
  const int lane = t & 63;
  const int w    = t >> 6;
  const int wm   = (w & 1) * 64;
  const int wn   = (w >> 1) * 64;
  const int q4   = lane >> 4;
  const int r16  = lane & 15;
  const int tm   = blockIdx.x * TM;
  const int tn   = blockIdx.y * TN;

  f32x4 acc[4][4] = {};

  for (int kt = 0; kt < Kdim; kt += TKK) {
    __syncthreads();
#pragma unroll
    for (int r = 0; r < 4; r++) {
      const int L = w * 256 + r * 64 + lane;
      const int R = L >> 3, c = (L & 7) * 8;
      stage16(A + (size_t)(tm + R) * Kdim + kt + c, As + L * 8);
      stage16(W + (size_t)(tn + R) * Kdim + kt + c, Ws + L * 8);
    }
    __syncthreads();
#pragma unroll
    for (int ks = 0; ks < TKK; ks += 32) {
      bf16x8 af[4], bfm[4];
#pragma unroll
      for (int i = 0; i < 4; i++)
        af[i] = *(const bf16x8*)(As + (wm + 16 * i + r16) * TKK + ks + q4 * 8);
#pragma unroll
      for (int j = 0; j < 4; j++)
        bfm[j] = *(const bf16x8*)(Ws + (wn + 16 * j + r16) * TKK + ks + q4 * 8);
#pragma unroll
      for (int i = 0; i < 4; i++)
#pragma unroll
        for (int j = 0; j < 4; j++)
          acc[i][j] = __builtin_amdgcn_mfma_f32_16x16x32_bf16(af[i], bfm[j], acc[i][j], 0, 0, 0);
    }
  }

  const int isf = (mode == 3) ? detect_isf(qdet) : 1;
#pragma unroll
  for (int j = 0; j < 4; j++) {
    const int col = tn + wn + 16 * j + r16;
    const float bv = (float)bias[col];
#pragma unroll
    for (int i = 0; i < 4; i++) {
      const int row0 = tm + wm + 16 * i + q4 * 4;
#pragma unroll
      for (int rr = 0; rr < 4; rr++) {
        const float v = acc[i][j][rr] + bv;
        const size_t off = (size_t)(row0 + rr) * Ndim + col;
        if (mode == 0) {
          ((bf16_t*)Cout)[off] = (bf16_t)v;
        } else if (mode == 6) {
          const int rowg = row0 + rr;
          if (col < 256) {
            ((bf16_t*)Cout)[(size_t)rowg * 256 + col] = (bf16_t)(v * kscale);
          } else {
            const int bb = rowg >> 9, tt = rowg & 511;
            const int c2 = col - 256;
            const int mm = c2 >> 5, ch = c2 & 31;
            ((bf16_t*)Cout2)[(((size_t)(bb * 8 + mm) * 32 + ch) << 9) + tt] = (bf16_t)v;
          }
        } else {
          if (isf) ((float*)Cout)[off] = v; else ((bf16_t*)Cout)[off] = (bf16_t)v;
        }
      }
    }
  }
}

// ============== VGPR-staged GEMM with dtype-flex A (Q-proj) ================
__global__ __launch_bounds__(256) void gemm_f32a(
    const void* __restrict__ Araw, const bf16_t* __restrict__ W,
    const bf16_t* __restrict__ bias, bf16_t* __restrict__ Cout,
    int Ndim, int Kdim, const void* __restrict__ qdet)
{
  __shared__ __align__(16) bf16_t As[TM * TKK];
  __shared__ __align__(16) bf16_t Ws[TN * TKK];
  const int t    = threadIdx.x;
  const int lane = t & 63;
  const int w    = t >> 6;
  const int wm   = (w & 1) * 64;
  const int wn   = (w >> 1) * 64;
  const int q4   = lane >> 4;
  const int r16  = lane & 15;
  const int tm   = blockIdx.x * TM;
  const int tn   = blockIdx.y * TN;
  const int aisf = detect_isf(qdet);

  f32x4 acc[4][4] = {};
  const int srow = t >> 1;
  const int skb  = (t & 1) * 32;

  for (int kt = 0; kt < Kdim; kt += TKK) {
    __syncthreads();
    if (aisf) {
      const float4* ga = (const float4*)((const float*)Araw + (size_t)(tm + srow) * Kdim + kt + skb);
#pragma unroll
      for (int kk = 0; kk < 8; kk++) {
        const float4 u = ga[kk];
        bf16x4 h = {(bf16_t)u.x, (bf16_t)u.y, (bf16_t)u.z, (bf16_t)u.w};
        *(bf16x4*)(As + srow * TKK + skb + kk * 4) = h;
      }
    } else {
      const uint4* ga = (const uint4*)((const bf16_t*)Araw + (size_t)(tm + srow) * Kdim + kt + skb);
      uint4* la = (uint4*)(As + srow * TKK + skb);
      la[0] = ga[0]; la[1] = ga[1]; la[2] = ga[2]; la[3] = ga[3];
    }
    {
      const uint4* gw = (const uint4*)(W + (size_t)(tn + srow) * Kdim + kt + skb);
      uint4* lw = (uint4*)(Ws + srow * TKK + skb);
      lw[0] = gw[0]; lw[1] = gw[1]; lw[2] = gw[2]; lw[3] = gw[3];
    }
    __syncthreads();
#pragma unroll
    for (int ks = 0; ks < TKK; ks += 32) {
      bf16x8 af[4], bfm[4];
#pragma unroll
      for (int i = 0; i < 4; i++)
        af[i] = *(const bf16x8*)(As + (wm + 16 * i + r16) * TKK + ks + q4 * 8);
#pragma unroll
      for (int j = 0; j < 4; j++)
        bfm[j] = *(const bf16x8*)(Ws + (wn + 16 * j + r16) * TKK + ks + q4 * 8);
#pragma unroll
      for (int i = 0; i < 4; i++)
#pragma unroll
        for (int j = 0; j < 4; j++)
          acc[i][j] = __builtin_amdgcn_mfma_f32_16x16x32_bf16(af[i], bfm[j], acc[i][j], 0, 0, 0);
    }
  }

#pragma unroll
  for (int j = 0; j < 4; j++) {
    const int col = tn + wn + 16 * j + r16;
    const float bv = (float)bias[col];
#pragma unroll
    for (int i = 0; i < 4; i++) {
      const int row0 = tm + wm + 16 * i + q4 * 4;
#pragma unroll
      for (int rr = 0; rr < 4; rr++)
        Cout[(size_t)(row0 + rr) * Ndim + col] = (bf16_t)(acc[i][j][rr] + bv);
    }
  }
}

// ==================== attention: LDS-free, per-head ========================
// K pre-scaled by CEXP. S^T = K·Q^T; p = exp2(s); O^T = V^T·P^T.
// grid (Ng/512, B*M); wave owns 128 q-rows (8 q-tiles) -> 8 independent
// MFMA->exp2->MFMA chains per K-tile (ILP) + 8x arithmetic per K/V load.
// Prefetch depth 2 (named A/B register sets — no runtime indexing) covers
// ~2x L2 latency; setprio(1) around compute favors in-compute waves
// (barrier-free kernel, waves drift out of phase — the m191 regime).
__global__ __launch_bounds__(256, 2) void attn_kernel(
    const bf16_t* __restrict__ Q, const bf16_t* __restrict__ Kk,
    const bf16_t* __restrict__ Vt, bf16_t* __restrict__ ctx)
{
  const int t = threadIdx.x;
  const int lane = t & 63, w = t >> 6;
  const int q4 = lane >> 4, r16 = lane & 15;
  const int bm = blockIdx.y;
  const int b = bm >> 3, m = bm & 7;
  const int q0 = blockIdx.x * 512 + w * 128;

  bf16x8 qf[8];
#pragma unroll
  for (int qt = 0; qt < 8; qt++)
    qf[qt] = *(const bf16x8*)(Q + ((size_t)(b * 8192 + q0 + qt * 16 + r16) * 256 + m * 32 + q4 * 8));

  f32x4 acc[8][2] = {};
  float lsum[8] = {0.f, 0.f, 0.f, 0.f, 0.f, 0.f, 0.f, 0.f};

  const bf16_t* kbase  = Kk + (size_t)b * 512 * 256 + m * 32 + (size_t)r16 * 256 + q4 * 8;
  const bf16_t* vbase0 = Vt + (size_t)bm * 32 * 512 + ((size_t)r16 << 9) + q4 * 4;
  const bf16_t* vbase1 = vbase0 + (16 << 9);

  // prefetch slots A (k0) and B (k0+16); over-reads past k=512 land in the
  // adjacent allocated ws regions (vt_g/blob) and are never consumed — safe.
  bf16x8 kfA = *(const bf16x8*)(kbase);
  bf16x4 v0A = *(const bf16x4*)(vbase0);
  bf16x4 v1A = *(const bf16x4*)(vbase1);
  bf16x8 kfB = *(const bf16x8*)(kbase + (size_t)16 * 256);
  bf16x4 v0B = *(const bf16x4*)(vbase0 + 16);
  bf16x4 v1B = *(const bf16x4*)(vbase1 + 16);

  for (int k0 = 0; k0 < 512; k0 += 32) {
    // ---- tile k0 from slot A; prefetch k0+32 into A ----
    const bf16x8 ka = kfA;
    const bf16x4 va0 = v0A, va1 = v1A;
    kfA = *(const bf16x8*)(kbase + (size_t)(k0 + 32) * 256);
    v0A = *(const bf16x4*)(vbase0 + k0 + 32);
    v1A = *(const bf16x4*)(vbase1 + k0 + 32);
    __builtin_amdgcn_s_setprio(1);
#pragma unroll
    for (int qt = 0; qt < 8; qt++) {
      f32x4 z = {};
      const f32x4 s = __builtin_amdgcn_mfma_f32_16x16x32_bf16(ka, qf[qt], z, 0, 0, 0);
      const float e0 = fexp2(s[0]), e1 = fexp2(s[1]);
      const float e2 = fexp2(s[2]), e3 = fexp2(s[3]);
      lsum[qt] += (e0 + e1) + (e2 + e3);
      // compiler pairs these casts into v_cvt_pk_bf16_f32 (m240)
      const bf16x4 p = {(bf16_t)e0, (bf16_t)e1, (bf16_t)e2, (bf16_t)e3};
      acc[qt][0] = mfma16x16x16(va0, p, acc[qt][0]);
      acc[qt][1] = mfma16x16x16(va1, p, acc[qt][1]);
    }
    __builtin_amdgcn_s_setprio(0);
    // ---- tile k0+16 from slot B; prefetch k0+48 into B ----
    const bf16x8 kb = kfB;
    const bf16x4 vb0 = v0B, vb1 = v1B;
    kfB = *(const bf16x8*)(kbase + (size_t)(k0 + 48) * 256);
    v0B = *(const bf16x4*)(vbase0 + k0 + 48);
    v1B = *(const bf16x4*)(vbase1 + k0 + 48);
    __builtin_amdgcn_s_setprio(1);
#pragma unroll
    for (int qt = 0; qt < 8; qt++) {
      f32x4 z = {};
      const f32x4 s = __builtin_amdgcn_mfma_f32_16x16x32_bf16(kb, qf[qt], z, 0, 0, 0);
      const float e0 = fexp2(s[0]), e1 = fexp2(s[1]);
      const float e2 = fexp2(s[2]), e3 = fexp2(s[3]);
      lsum[qt] += (e0 + e1) + (e2 + e3);
      const bf16x4 p = {(bf16_t)e0, (bf16_t)e1, (bf16_t)e2, (bf16_t)e3};
      acc[qt][0] = mfma16x16x16(vb0, p, acc[qt][0]);
      acc[qt][1] = mfma16x16x16(vb1, p, acc[qt][1]);
    }
    __builtin_amdgcn_s_setprio(0);
  }

#pragma unroll
  for (int qt = 0; qt < 8; qt++) {
    float v = lsum[qt];
    v += __shfl_xor(v, 16, 64);
    v += __shfl_xor(v, 32, 64);
    const float inv = 1.0f / v;
    const size_t row = (size_t)b * 8192 + q0 + qt * 16 + r16;
    bf16x4 o0, o1;
#pragma unroll
    for (int rr = 0; rr < 4; rr++) {
      o0[rr] = (bf16_t)(acc[qt][0][rr] * inv);
      o1[rr] = (bf16_t)(acc[qt][1][rr] * inv);
    }
    *(bf16x4*)(ctx + row * 256 + m * 32 + q4 * 4)      = o0;
    *(bf16x4*)(ctx + row * 256 + m * 32 + 16 + q4 * 4) = o1;
  }
}

// ================= residual + LayerNorm -> gq hi/lo split ==================
// lane owns 4 CONTIGUOUS columns -> float4/bf16x4 vector loads+stores
__global__ __launch_bounds__(256) void ln_kernel(
    const bf16_t* __restrict__ y2, const void* __restrict__ query,
    const void* __restrict__ g, const void* __restrict__ beta,
    bf16_t* __restrict__ gqh, bf16_t* __restrict__ gql)
{
  const int isf = detect_isf(query);
  const int rowb = blockIdx.x * 4 + (threadIdx.x >> 6);
  const int lane = threadIdx.x & 63;
  const size_t base = (size_t)rowb * 256;
  const int c0 = lane * 4;
  float x[4];
  {
    const bf16x4 yv = *(const bf16x4*)(y2 + base + c0);
    if (isf) {
      const float4 qv = *(const float4*)((const float*)query + base + c0);
      x[0] = qv.x + (float)yv[0]; x[1] = qv.y + (float)yv[1];
      x[2] = qv.z + (float)yv[2]; x[3] = qv.w + (float)yv[3];
    } else {
      const bf16x4 qv = *(const bf16x4*)((const bf16_t*)query + base + c0);
#pragma unroll
      for (int k = 0; k < 4; k++) x[k] = (float)qv[k] + (float)yv[k];
    }
  }
  float s = x[0] + x[1] + x[2] + x[3];
  for (int d = 1; d < 64; d <<= 1) s += __shfl_xor(s, d, 64);
  const float mu = s * (1.0f / 256.0f);
  float vs = 0.f;
#pragma unroll
  for (int k = 0; k < 4; k++) { const float d = x[k] - mu; vs += d * d; }
  for (int d = 1; d < 64; d <<= 1) vs += __shfl_xor(vs, d, 64);
  const float rstd = rsqrtf(vs * (1.0f / 256.0f) + 1e-5f);
  float gw[4], bb[4];
  if (isf) {
    const float4 gg = *(const float4*)((const float*)g + c0);
    const float4 bv = *(const float4*)((const float*)beta + c0);
    gw[0] = gg.x; gw[1] = gg.y; gw[2] = gg.z; gw[3] = gg.w;
    bb[0] = bv.x; bb[1] = bv.y; bb[2] = bv.z; bb[3] = bv.w;
  } else {
    const bf16x4 gg = *(const bf16x4*)((const bf16_t*)g + c0);
    const bf16x4 bv = *(const bf16x4*)((const bf16_t*)beta + c0);
#pragma unroll
    for (int k = 0; k < 4; k++) { gw[k] = (float)gg[k]; bb[k] = (float)bv[k]; }
  }
  bf16x4 hi4, lo4;
#pragma unroll
  for (int k = 0; k < 4; k++) {
    const float gv = (x[k] - mu) * rstd * gw[k] + bb[k];
    const bf16_t hi = (bf16_t)gv;
    hi4[k] = hi;
    lo4[k] = (bf16_t)(gv - (float)hi);
  }
  *(bf16x4*)(gqh + base + c0) = hi4;
  *(bf16x4*)(gql + base + c0) = lo4;
}

// ===== fused offs/attw GEMM: ysamp = gqh*(Wh+Wl)^T + gql*Wh^T + bias =======
// epilogue scatters into per-(b,m) layout: ys2[(bm*8192+q)*16 + inner],
// inner 0..7 = offs(p*2+d), 8..11 = attw logits, 12..15 pad. Sampler then
// reads 48B contiguous per thread (vs 48B scattered in a 512B row shared
// across 8 m-blocks on different XCDs).
__global__ __launch_bounds__(256) void gemm_offs(
    const bf16_t* __restrict__ Ahg, const bf16_t* __restrict__ Alg,
    const bf16_t* __restrict__ Whg, const bf16_t* __restrict__ Wlg,
    const bf16_t* __restrict__ bias, float* __restrict__ Cout)
{
  __shared__ __align__(16) bf16_t Ah[128 * 64];
  __shared__ __align__(16) bf16_t Al[128 * 64];
  __shared__ __align__(16) bf16_t Wh[128 * 64];
  __shared__ __align__(16) bf16_t Wl[128 * 64];
  const int t    = threadIdx.x;
  const int lane = t & 63;
  const int w    = t >> 6;
  const int wm   = (w & 1) * 64;
  const int wn   = (w >> 1) * 64;
  const int q4   = lane >> 4;
  const int r16  = lane & 15;
  const int tm   = blockIdx.x * 128;

  f32x4 acc[4][4] = {};
  const int srow = t >> 1;
  const int skb  = (t & 1) * 32;

  for (int kt = 0; kt < 256; kt += 64) {
    __syncthreads();
    {
      const uint4* g0 = (const uint4*)(Ahg + (size_t)(tm + srow) * 256 + kt + skb);
      uint4* l0 = (uint4*)(Ah + srow * 64 + skb);
      l0[0] = g0[0]; l0[1] = g0[1]; l0[2] = g0[2]; l0[3] = g0[3];
      const uint4* g1 = (const uint4*)(Alg + (size_t)(tm + srow) * 256 + kt + skb);
      uint4* l1 = (uint4*)(Al + srow * 64 + skb);
      l1[0] = g1[0]; l1[1] = g1[1]; l1[2] = g1[2]; l1[3] = g1[3];
      const uint4* g2 = (const uint4*)(Whg + (size_t)srow * 256 + kt + skb);
      uint4* l2 = (uint4*)(Wh + srow * 64 + skb);
      l2[0] = g2[0]; l2[1] = g2[1]; l2[2] = g2[2]; l2[3] = g2[3];
      const uint4* g3 = (const uint4*)(Wlg + (size_t)srow * 256 + kt + skb);
      uint4* l3 = (uint4*)(Wl + srow * 64 + skb);
      l3[0] = g3[0]; l3[1] = g3[1]; l3[2] = g3[2]; l3[3] = g3[3];
    }
    __syncthreads();
#pragma unroll
    for (int ks = 0; ks < 64; ks += 32) {
      bf16x8 ah[4], al[4], bh[4], bl[4];
#pragma unroll
      for (int i = 0; i < 4; i++) {
        ah[i] = *(const bf16x8*)(Ah + (wm + 16 * i + r16) * 64 + ks + q4 * 8);
        al[i] = *(const bf16x8*)(Al + (wm + 16 * i + r16) * 64 + ks + q4 * 8);
      }
#pragma unroll
      for (int j = 0; j < 4; j++) {
        bh[j] = *(const bf16x8*)(Wh + (wn + 16 * j + r16) * 64 + ks + q4 * 8);
        bl[j] = *(const bf16x8*)(Wl + (wn + 16 * j + r16) * 64 + ks + q4 * 8);
      }
#pragma unroll
      for (int i = 0; i < 4; i++)
#pragma unroll
        for (int j = 0; j < 4; j++) {
          f32x4 a = acc[i][j];
          a = __builtin_amdgcn_mfma_f32_16x16x32_bf16(al[i], bh[j], a, 0, 0, 0);
          a = __builtin_amdgcn_mfma_f32_16x16x32_bf16(ah[i], bl[j], a, 0, 0, 0);
          a = __builtin_amdgcn_mfma_f32_16x16x32_bf16(ah[i], bh[j], a, 0, 0, 0);
          acc[i][j] = a;
        }
    }
  }

#pragma unroll
  for (int j = 0; j < 4; j++) {
    const int col = wn + 16 * j + r16;
    const float bv = (float)bias[col];
    // remap col -> (m, inner); cols >=96 are dead (zero weights+bias)
    const int live  = (col < 96) ? 1 : 0;
    const int moff  = (col < 64) ? (col >> 3) : ((col - 64) >> 2);
    const int inner = (col < 64) ? (col & 7) : (8 + (col & 3));
#pragma unroll
    for (int i = 0; i < 4; i++) {
      const int row0 = tm + wm + 16 * i + q4 * 4;
#pragma unroll
      for (int rr = 0; rr < 4; rr++) {
        if (live) {
          const int row = row0 + rr;
          const int bq = row >> 13, q = row & 8191;
          Cout[(((size_t)(bq * 8 + moff) << 13) + q) * 16 + inner] = acc[i][j][rr] + bv;
        }
      }
    }
  }
}

// ============ value transpose (B,C,H,W) -> (B,M,H,W,Ch) bf16 ===============
// vectorized: 16-32B global loads, ds_write_b128 into [ch][ww] tile,
// scalar LDS gather (<=4-way), bf16x8 global stores (2KB contiguous/wave)
__global__ __launch_bounds__(256) void transpose_value(
    const void* __restrict__ V, bf16_t* __restrict__ Vp, const void* __restrict__ qdet)
{
  __shared__ __align__(16) bf16_t tile[32][136];
  const int isf = detect_isf(qdet);
  const int bid = blockIdx.x;
  const int h = bid & 127;
  const int bm = bid >> 7;
  const int b = bm >> 3, mm = bm & 7;
  const int t = threadIdx.x;
  // load: thread owns (ch = t>>3, ww0 = (t&7)*16) -> 16 contiguous ww
  const int ch  = t >> 3;
  const int ww0 = (t & 7) * 16;
  const size_t ibase = (((size_t)b * 256 + mm * 32 + ch) * 128 + h) * 128 + ww0;
  if (isf) {
    const float4* src = (const float4*)((const float*)V + ibase);
    bf16x8 h0, h1;
#pragma unroll
    for (int k = 0; k < 2; k++) {
      const float4 u0 = src[k * 2], u1 = src[k * 2 + 1];
      bf16x8 hh = {(bf16_t)u0.x, (bf16_t)u0.y, (bf16_t)u0.z, (bf16_t)u0.w,
                   (bf16_t)u1.x, (bf16_t)u1.y, (bf16_t)u1.z, (bf16_t)u1.w};
      if (k == 0) h0 = hh; else h1 = hh;
    }
    *(bf16x8*)(&tile[ch][ww0])     = h0;
    *(bf16x8*)(&tile[ch][ww0 + 8]) = h1;
  } else {
    const bf16x8* src = (const bf16x8*)((const bf16_t*)V + ibase);
    *(bf16x8*)(&tile[ch][ww0])     = src[0];
    *(bf16x8*)(&tile[ch][ww0 + 8]) = src[1];
  }
  __syncthreads();
  // store: thread owns (ww = t>>1, c0 = (t&1)*16) -> 32 contiguous ch out
  const size_t base = ((size_t)bm * 128 + h) * 4096;
  const int ww = t >> 1;
  const int c0 = (t & 1) * 16;
  bf16x8 o0, o1;
#pragma unroll
  for (int e = 0; e < 8; e++) { o0[e] = tile[c0 + e][ww]; o1[e] = tile[c0 + 8 + e][ww]; }
  *(bf16x8*)(Vp + base + ww * 32 + c0)     = o0;
  *(bf16x8*)(Vp + base + ww * 32 + c0 + 8) = o1;
}

// ===================== deformable bilinear sampler =========================
// Channel-split: 2 threads/query (hf = channel half), grid 2048 -> 8192 waves
// = 8 waves/SIMD ceiling (was 4). Latency-bound gather needs the TLP: R5
// showed occupancy capped at 34% with 1024 blocks. Same cache lines touched;
// body arithmetic identical to R2's proven divergent loop. ys2 is the packed
// per-(b,m) 64B/query layout (read once, coalesced).
__global__ __launch_bounds__(256) void sampler(
    const float* __restrict__ ys2, const void* __restrict__ refp,
    const bf16_t* __restrict__ vperm, bf16_t* __restrict__ outs,
    const void* __restrict__ qdet)
{
  const int isf = detect_isf(qdet);
  const int t = threadIdx.x;
  const int wg = blockIdx.x;
  const int bm  = (wg & 7) + ((wg >> 9) << 3);  // XCD = wg%8 = bm%8
  const int mid = (wg >> 3) & 63;
  const int qt  = mid >> 1;
  const int hf  = mid & 1;                      // channel half
  const int b = bm >> 3, m = bm & 7;
  const int qq = qt * 256 + t;
  const size_t row = (size_t)b * 8192 + qq;
  const float* y16 = ys2 + (((size_t)bm << 13) + qq) * 16;
  const float rx = ldf(refp, row * 2 + 0, isf);
  const float ry = ldf(refp, row * 2 + 1, isf);

  const float4 off01 = *(const float4*)(y16 + 0);
  const float4 off23 = *(const float4*)(y16 + 4);
  const float4 lg    = *(const float4*)(y16 + 8);

  const float mx = fmaxf(fmaxf(lg.x, lg.y), fmaxf(lg.z, lg.w));
  const float e0 = __expf(lg.x - mx), e1 = __expf(lg.y - mx);
  const float e2 = __expf(lg.z - mx), e3 = __expf(lg.w - mx);
  const float inv = 1.0f / (e0 + e1 + e2 + e3);
  const float aw[4] = {e0 * inv, e1 * inv, e2 * inv, e3 * inv};
  const float ox[4] = {off01.x, off01.z, off23.x, off23.z};
  const float oy[4] = {off01.y, off01.w, off23.y, off23.w};

  float acc[16];
#pragma unroll
  for (int ch = 0; ch < 16; ch++) acc[ch] = 0.0f;

  const bf16_t* vbase = vperm + (size_t)bm * (128 * 128 * 32) + hf * 16;

  for (int p = 0; p < 4; p++) {
    const float gx = (rx + ox[p]) * 128.0f - 0.5f;
    const float gy = (ry + oy[p]) * 128.0f - 0.5f;
    const float x0f = floorf(gx), y0f = floorf(gy);
    const int x0 = (int)x0f, y0i = (int)y0f;
    const float wx1 = gx - x0f, wx0 = 1.0f - wx1;
    const float wy1 = gy - y0f, wy0 = 1.0f - wy1;
    const float a = aw[p];
    for (int cy = 0; cy < 2; cy++) {
      const int yy = y0i + cy;
      if (yy < 0 || yy >= 128) continue;
      const float wy = cy ? wy1 : wy0;
      for (int cx = 0; cx < 2; cx++) {
        const int xx = x0 + cx;
        if (xx < 0 || xx >= 128) continue;
        const float wgt = a * wy * (cx ? wx1 : wx0);
        const bf16x8* src8 = (const bf16x8*)(vbase + ((size_t)yy * 128 + xx) * 32);
        const bf16x8 d0 = src8[0];
        const bf16x8 d1 = src8[1];
#pragma unroll
        for (int e = 0; e < 8; e++) {
          acc[e]     += wgt * (float)d0[e];
          acc[8 + e] += wgt * (float)d1[e];
        }
      }
    }
  }

  const size_t obase = (size_t)b * 8192;
#pragma unroll
  for (int ch = 0; ch < 16; ch++) {
    const int chg = hf * 16 + ch;
    const size_t orow = obase + (size_t)(chg * 8 + m) * 32 + qt;
    outs[orow * 256 + t] = (bf16_t)acc[ch];
  }
}

// ===========================================================================
extern "C" void kernel_launch(void* const* d_in, const int* in_sizes, int n_in,
                              void* d_out, int out_size, void* d_ws, size_t ws_size,
                              hipStream_t stream) {
  const void* query = d_in[0];
  const void* value = d_in[1];
  const void* refp  = d_in[2];
  const void* trajp = d_in[3];
  const void* in_w  = d_in[4];
  const void* in_b  = d_in[5];
  const void* mow   = d_in[6];
  const void* mob   = d_in[7];
  const void* lng   = d_in[8];
  const void* lnb   = d_in[9];
  const void* tw    = d_in[10];
  const void* tb    = d_in[11];
  const void* ow    = d_in[12];
  const void* ob    = d_in[13];
  const void* aww   = d_in[14];
  const void* awb   = d_in[15];
  const void* outw  = d_in[16];
  const void* outb  = d_in[17];

  char* base = (char*)d_ws;
  float*  ysamp = (float*)(base);
  bf16_t* qout  = (bf16_t*)(base + 16777216);
  bf16_t* ctx   = (bf16_t*)(base + 33554432);
  bf16_t* y2    = (bf16_t*)(base + 50331648);
  bf16_t* tf_ws = (bf16_t*)(base + 67108864);
  bf16_t* k_ws  = (bf16_t*)(base + 68157440);
  bf16_t* vt_g  = (bf16_t*)(base + 69206016);
  bf16_t* blob  = (bf16_t*)(base + 70254592);

  bf16_t* gqh   = qout;
  bf16_t* gql   = ctx;
  bf16_t* vperm = (bf16_t*)(base + 16777216);   // 32MB, alias R1+R2
  bf16_t* outs  = y2;

  bf16_t* inw_bf  = blob;
  bf16_t* inb_bf  = blob + 196608;
  bf16_t* mow_bf  = blob + 197376;
  bf16_t* mob_bf  = blob + 262912;
  bf16_t* outw_bf = blob + 263168;
  bf16_t* outb_bf = blob + 328704;
  bf16_t* wph     = blob + 328960;
  bf16_t* wpl     = blob + 361728;
  bf16_t* bpad    = blob + 394496;

  prep_all<<<dim3(2498), dim3(256), 0, stream>>>(
      query, in_w, in_b, mow, mob, outw, outb, trajp, tw, tb,
      ow, aww, ob, awb, blob, tf_ws, wph, wpl, bpad);
  gemm_async<<<dim3(16, 4), dim3(256), 0, stream>>>(
      tf_ws, inw_bf + 65536, inb_bf + 256, (void*)k_ws, (void*)vt_g, 512, 256, 6, CEXP, query);
  gemm_f32a<<<dim3(256, 2), dim3(256), 0, stream>>>(
      query, inw_bf, inb_bf, qout, 256, 256, query);
  attn_kernel<<<dim3(16, 32), dim3(256), 0, stream>>>(qout, k_ws, vt_g, ctx);
  gemm_async<<<dim3(256, 2), dim3(256), 0, stream>>>(
      ctx, mow_bf, mob_bf, (void*)y2, nullptr, 256, 256, 0, 1.0f, query);
  ln_kernel<<<dim3(8192), dim3(256), 0, stream>>>(y2, query, lng, lnb, gqh, gql);
  gemm_offs<<<dim3(256, 1), dim3(256), 0, stream>>>(gqh, gql, wph, wpl, bpad, ysamp);
  transpose_value<<<dim3(4096), dim3(256), 0, stream>>>(value, vperm, query);
  sampler<<<dim3(2048), dim3(256), 0, stream>>>(ysamp, refp, vperm, outs, query);
  gemm_async<<<dim3(256, 2), dim3(256), 0, stream>>>(
      outs, outw_bf, outb_bf, d_out, nullptr, 256, 256, 3, 1.0f, query);
}

// Round 7
// 333.523 us; speedup vs baseline: 1.0429x; 1.0083x over previous
//
#include <hip/hip_runtime.h>
#include <hip/hip_bf16.h>
#include <stdint.h>

typedef __bf16 bf16_t;
typedef __bf16 bf16x8 __attribute__((ext_vector_type(8)));
typedef __bf16 bf16x4 __attribute__((ext_vector_type(4)));
typedef float f32x4 __attribute__((ext_vector_type(4)));

// Shapes: B=4 Ng=8192 C=256 H=W=128 Nt=512 M=8 P=4 Ch=32
#define CEXP 0.25506807186679906f  // (1/sqrt(32)) * log2(e), folded into K

__device__ __forceinline__ float ldf(const void* p, size_t i, int isf) {
  return isf ? ((const float*)p)[i] : (float)((const bf16_t*)p)[i];
}

// per-wave dtype detect on query[0:128 elems] — deterministic everywhere
__device__ __forceinline__ int detect_isf(const void* q) {
  const uint16_t* u = (const uint16_t*)q;
  const int lane = threadIdx.x & 63;
  const uint16_t v = u[2 * lane];
  const int e = (v >> 7) & 0xFF;
  const int weird = (e >= 0x86 || (v != 0 && e <= 0x65)) ? 1 : 0;
  return (__popcll(__ballot(weird)) >= 16) ? 1 : 0;
}

__device__ __forceinline__ float fexp2(float x) {
#if __has_builtin(__builtin_amdgcn_exp2f)
  return __builtin_amdgcn_exp2f(x);
#else
  return exp2f(x);
#endif
}

// 16x16x16 bf16 MFMA: C-layout of a 16x16 tile == B-layout of this shape.
__device__ __forceinline__ f32x4 mfma16x16x16(bf16x4 a, bf16x4 b, f32x4 c) {
#if __has_builtin(__builtin_amdgcn_mfma_f32_16x16x16_bf16)
  return __builtin_amdgcn_mfma_f32_16x16x16_bf16(a, b, c, 0, 0, 0);
#else
  typedef short s16x4 __attribute__((ext_vector_type(4)));
  return __builtin_amdgcn_mfma_f32_16x16x16bf16_1k(
      __builtin_bit_cast(s16x4, a), __builtin_bit_cast(s16x4, b), c, 0, 0, 0);
#endif
}

// async global->LDS, 16B per lane
__device__ __forceinline__ void stage16(const bf16_t* g, bf16_t* l) {
  __builtin_amdgcn_global_load_lds((const __attribute__((address_space(1))) void*)g,
                                   (__attribute__((address_space(3))) void*)l, 16, 0, 0);
}

// == merged prep: weights->bf16 | tf proj | wpad hi/lo | value transpose ====
// transpose_value folded in (bid >= 2370+128): vperm no longer aliases
// gqh/gql (moved to +128MiB), so the transpose can run at t=0 overlapped
// with the (tiny) prep work instead of serialized mid-chain.
__global__ __launch_bounds__(256) void prep_all(
    const void* __restrict__ query,
    const void* in_w, const void* in_b, const void* mow, const void* mob,
    const void* outw, const void* outb,
    const void* trajp, const void* tw, const void* tb,
    const void* offs_w, const void* attw_w, const void* offs_b, const void* attw_b,
    bf16_t* __restrict__ blob, bf16_t* __restrict__ tf,
    bf16_t* __restrict__ Wph, bf16_t* __restrict__ Wpl, bf16_t* __restrict__ bp,
    const void* __restrict__ V, bf16_t* __restrict__ Vp)
{
  __shared__ __align__(16) bf16_t tile[32][136];
  const int isf = detect_isf(query);
  const int bid = blockIdx.x;
  if (bid < 322) {
    const int g = (bid * 256 + threadIdx.x) * 4;
    if (g >= 328960) return;
    const void* src; size_t off;
    if      (g < 196608) { src = in_w; off = g; }
    else if (g < 197376) { src = in_b; off = g - 196608; }
    else if (g < 262912) { src = mow;  off = g - 197376; }
    else if (g < 263168) { src = mob;  off = g - 262912; }
    else if (g < 328704) { src = outw; off = g - 263168; }
    else                 { src = outb; off = g - 328704; }
#pragma unroll
    for (int k = 0; k < 4; k++) blob[g + k] = (bf16_t)ldf(src, off + k, isf);
  } else if (bid < 322 + 2048) {
    const int rowb = bid - 322;
    const int c = threadIdx.x;
    const float x = ldf(trajp, rowb * 2 + 0, isf);
    const float y = ldf(trajp, rowb * 2 + 1, isf);
    const float v = x * ldf(tw, c * 2 + 0, isf) + y * ldf(tw, c * 2 + 1, isf) + ldf(tb, c, isf);
    tf[(size_t)rowb * 256 + c] = (bf16_t)v;
  } else if (bid < 2498) {
    const int idx = (bid - 2370) * 256 + threadIdx.x;
    const int rowp = idx >> 8, c = idx & 255;
    float v = 0.0f;
    if (rowp < 64)      v = ldf(offs_w, rowp * 256 + c, isf);
    else if (rowp < 96) v = ldf(attw_w, (rowp - 64) * 256 + c, isf);
    const bf16_t hi = (bf16_t)v;
    Wph[idx] = hi;
    Wpl[idx] = (bf16_t)(v - (float)hi);
    if (idx < 128) {
      float bv = 0.0f;
      if (idx < 64)      bv = ldf(offs_b, idx, isf);
      else if (idx < 96) bv = ldf(attw_b, idx - 64, isf);
      bp[idx] = (bf16_t)bv;
    }
  } else {
    // ---- value transpose (B,C,H,W) -> (B,M,H,W,Ch), vectorized ----
    const int vb = bid - 2498;
    const int h = vb & 127;
    const int bm = vb >> 7;
    const int b = bm >> 3, mm = bm & 7;
    const int t = threadIdx.x;
    const int ch  = t >> 3;
    const int ww0 = (t & 7) * 16;
    const size_t ibase = (((size_t)b * 256 + mm * 32 + ch) * 128 + h) * 128 + ww0;
    if (isf) {
      const float4* src = (const float4*)((const float*)V + ibase);
      bf16x8 h0, h1;
#pragma unroll
      for (int k = 0; k < 2; k++) {
        const float4 u0 = src[k * 2], u1 = src[k * 2 + 1];
        bf16x8 hh = {(bf16_t)u0.x, (bf16_t)u0.y, (bf16_t)u0.z, (bf16_t)u0.w,
                     (bf16_t)u1.x, (bf16_t)u1.y, (bf16_t)u1.z, (bf16_t)u1.w};
        if (k == 0) h0 = hh; else h1 = hh;
      }
      *(bf16x8*)(&tile[ch][ww0])     = h0;
      *(bf16x8*)(&tile[ch][ww0 + 8]) = h1;
    } else {
      const bf16x8* src = (const bf16x8*)((const bf16_t*)V + ibase);
      *(bf16x8*)(&tile[ch][ww0])     = src[0];
      *(bf16x8*)(&tile[ch][ww0 + 8]) = src[1];
    }
    __syncthreads();
    const size_t base = ((size_t)bm * 128 + h) * 4096;
    const int ww = t >> 1;
    const int c0 = (t & 1) * 16;
    bf16x8 o0, o1;
#pragma unroll
    for (int e = 0; e < 8; e++) { o0[e] = tile[c0 + e][ww]; o1[e] = tile[c0 + 8 + e][ww]; }
    *(bf16x8*)(Vp + base + ww * 32 + c0)     = o0;
    *(bf16x8*)(Vp + base + ww * 32 + c0 + 8) = o1;
  }
}

// ============== async-staged bf16 GEMM: C = A@W^T + bias ===================
// mode 0: bf16 store; mode 3: dtype-of-query store
#define TM 128
#define TN 128
#define TKK 64

__global__ __launch_bounds__(256) void gemm_async(
    const bf16_t* __restrict__ A, const bf16_t* __restrict__ W,
    const bf16_t* __restrict__ bias, void* __restrict__ Cout,
    void* __restrict__ Cout2, int Ndim, int Kdim, int mode, float kscale,
    const void* __restrict__ qdet)
{
  __shared__ __align__(16) bf16_t As[TM * TKK];
  __shared__ __align__(16) bf16_t Ws[TN * TKK];
  const int t    = threadIdx.x;
  const int lane = t & 63;
  const int w    = t >> 6;
  const int wm   = (w & 1) * 64;
  const int wn   = (w >> 1) * 64;
  const int q4   = lane >> 4;
  const int r16  = lane & 15;
  const int tm   = blockIdx.x * TM;
  const int tn   = blockIdx.y * TN;

  f32x4 acc[4][4] = {};

  for (int kt = 0; kt < Kdim; kt += TKK) {
    __syncthreads();
#pragma unroll
    for (int r = 0; r < 4; r++) {
      const int L = w * 256 + r * 64 + lane;
      const int R = L >> 3, c = (L & 7) * 8;
      stage16(A + (size_t)(tm + R) * Kdim + kt + c, As + L * 8);
      stage16(W + (size_t)(tn + R) * Kdim + kt + c, Ws + L * 8);
    }
    __syncthreads();
#pragma unroll
    for (int ks = 0; ks < TKK; ks += 32) {
      bf16x8 af[4], bfm[4];
#pragma unroll
      for (int i = 0; i < 4; i++)
        af[i] = *(const bf16x8*)(As + (wm + 16 * i + r16) * TKK + ks + q4 * 8);
#pragma unroll
      for (int j = 0; j < 4; j++)
        bfm[j] = *(const bf16x8*)(Ws + (wn + 16 * j + r16) * TKK + ks + q4 * 8);
#pragma unroll
      for (int i = 0; i < 4; i++)
#pragma unroll
        for (int j = 0; j < 4; j++)
          acc[i][j] = __builtin_amdgcn_mfma_f32_16x16x32_bf16(af[i], bfm[j], acc[i][j], 0, 0, 0);
    }
  }

  const int isf = (mode == 3) ? detect_isf(qdet) : 1;
#pragma unroll
  for (int j = 0; j < 4; j++) {
    const int col = tn + wn + 16 * j + r16;
    const float bv = (float)bias[col];
#pragma unroll
    for (int i = 0; i < 4; i++) {
      const int row0 = tm + wm + 16 * i + q4 * 4;
#pragma unroll
      for (int rr = 0; rr < 4; rr++) {
        const float v = acc[i][j][rr] + bv;
        const size_t off = (size_t)(row0 + rr) * Ndim + col;
        if (mode == 0) {
          ((bf16_t*)Cout)[off] = (bf16_t)v;
        } else {
          if (isf) ((float*)Cout)[off] = v; else ((bf16_t*)Cout)[off] = (bf16_t)v;
        }
      }
    }
  }
}

// ========== merged Q-proj (f32a path) + K/V-proj (mode-6 path) =============
// blocks 0..511: Q = query@wq^T+bq (dtype-flex A, VGPR staging)
// blocks 512..575: [K|V] = tf@wkv^T+bkv, K scaled by CEXP, V transposed.
// Both depend only on prep; merging hides the 64-block KV GEMM (1/4 of the
// machine if launched alone) under Q-proj's full occupancy.
__global__ __launch_bounds__(256) void gemm_qkv(
    const void* __restrict__ Araw, const bf16_t* __restrict__ Wq,
    const bf16_t* __restrict__ bq, bf16_t* __restrict__ Cq,
    const bf16_t* __restrict__ Atf, const bf16_t* __restrict__ Wkv,
    const bf16_t* __restrict__ bkv, bf16_t* __restrict__ Kout,
    bf16_t* __restrict__ Vtout, float kscale, const void* __restrict__ qdet)
{
  __shared__ __align__(16) bf16_t As[TM * TKK];
  __shared__ __align__(16) bf16_t Ws[TN * TKK];
  const int t    = threadIdx.x;
  const int lane = t & 63;
  const int w    = t >> 6;
  const int wm   = (w & 1) * 64;
  const int wn   = (w >> 1) * 64;
  const int q4   = lane >> 4;
  const int r16  = lane & 15;
  const int blk  = blockIdx.x;

  f32x4 acc[4][4] = {};

  if (blk < 512) {
    // ---------------- Q-proj: A dtype-flex, K=256, N=256 ----------------
    const int tm = (blk >> 1) * TM;
    const int tn = (blk & 1) * TN;
    const int aisf = detect_isf(qdet);
    const int srow = t >> 1;
    const int skb  = (t & 1) * 32;

    for (int kt = 0; kt < 256; kt += TKK) {
      __syncthreads();
      if (aisf) {
        const float4* ga = (const float4*)((const float*)Araw + (size_t)(tm + srow) * 256 + kt + skb);
#pragma unroll
        for (int kk = 0; kk < 8; kk++) {
          const float4 u = ga[kk];
          bf16x4 h = {(bf16_t)u.x, (bf16_t)u.y, (bf16_t)u.z, (bf16_t)u.w};
          *(bf16x4*)(As + srow * TKK + skb + kk * 4) = h;
        }
      } else {
        const uint4* ga = (const uint4*)((const bf16_t*)Araw + (size_t)(tm + srow) * 256 + kt + skb);
        uint4* la = (uint4*)(As + srow * TKK + skb);
        la[0] = ga[0]; la[1] = ga[1]; la[2] = ga[2]; la[3] = ga[3];
      }
      {
        const uint4* gw = (const uint4*)(Wq + (size_t)(tn + srow) * 256 + kt + skb);
        uint4* lw = (uint4*)(Ws + srow * TKK + skb);
        lw[0] = gw[0]; lw[1] = gw[1]; lw[2] = gw[2]; lw[3] = gw[3];
      }
      __syncthreads();
#pragma unroll
      for (int ks = 0; ks < TKK; ks += 32) {
        bf16x8 af[4], bfm[4];
#pragma unroll
        for (int i = 0; i < 4; i++)
          af[i] = *(const bf16x8*)(As + (wm + 16 * i + r16) * TKK + ks + q4 * 8);
#pragma unroll
        for (int j = 0; j < 4; j++)
          bfm[j] = *(const bf16x8*)(Ws + (wn + 16 * j + r16) * TKK + ks + q4 * 8);
#pragma unroll
        for (int i = 0; i < 4; i++)
#pragma unroll
          for (int j = 0; j < 4; j++)
            acc[i][j] = __builtin_amdgcn_mfma_f32_16x16x32_bf16(af[i], bfm[j], acc[i][j], 0, 0, 0);
      }
    }

#pragma unroll
    for (int j = 0; j < 4; j++) {
      const int col = tn + wn + 16 * j + r16;
      const float bv = (float)bq[col];
#pragma unroll
      for (int i = 0; i < 4; i++) {
        const int row0 = tm + wm + 16 * i + q4 * 4;
#pragma unroll
        for (int rr = 0; rr < 4; rr++)
          Cq[(size_t)(row0 + rr) * 256 + col] = (bf16_t)(acc[i][j][rr] + bv);
      }
    }
  } else {
    // -------- K/V-proj: async-staged, M=2048 N=512 K=256, mode-6 --------
    const int k = blk - 512;
    const int tm = (k & 15) * TM;
    const int tn = (k >> 4) * TN;

    for (int kt = 0; kt < 256; kt += TKK) {
      __syncthreads();
#pragma unroll
      for (int r = 0; r < 4; r++) {
        const int L = w * 256 + r * 64 + lane;
        const int R = L >> 3, c = (L & 7) * 8;
        stage16(Atf + (size_t)(tm + R) * 256 + kt + c, As + L * 8);
        stage16(Wkv + (size_t)(tn + R) * 256 + kt + c, Ws + L * 8);
      }
      __syncthreads();
#pragma unroll
      for (int ks = 0; ks < TKK; ks += 32) {
        bf16x8 af[4], bfm[4];
#pragma unroll
        for (int i = 0; i < 4; i++)
          af[i] = *(const bf16x8*)(As + (wm + 16 * i + r16) * TKK + ks + q4 * 8);
#pragma unroll
        for (int j = 0; j < 4; j++)
          bfm[j] = *(const bf16x8*)(Ws + (wn + 16 * j + r16) * TKK + ks + q4 * 8);
#pragma unroll
        for (int i = 0; i < 4; i++)
#pragma unroll
          for (int j = 0; j < 4; j++)
            acc[i][j] = __builtin_amdgcn_mfma_f32_16x16x32_bf16(af[i], bfm[j], acc[i][j], 0, 0, 0);
      }
    }

#pragma unroll
    for (int j = 0; j < 4; j++) {
      const int col = tn + wn + 16 * j + r16;
      const float bv = (float)bkv[col];
#pragma unroll
      for (int i = 0; i < 4; i++) {
        const int row0 = tm + wm + 16 * i + q4 * 4;
#pragma unroll
        for (int rr = 0; rr < 4; rr++) {
          const float v = acc[i][j][rr] + bv;
          const int rowg = row0 + rr;
          if (col < 256) {
            Kout[(size_t)rowg * 256 + col] = (bf16_t)(v * kscale);
          } else {
            const int bb = rowg >> 9, tt = rowg & 511;
            const int c2 = col - 256;
            const int mm = c2 >> 5, ch = c2 & 31;
            Vtout[(((size_t)(bb * 8 + mm) * 32 + ch) << 9) + tt] = (bf16_t)v;
          }
        }
      }
    }
  }
}

// ==================== attention: LDS-free, per-head ========================
// K pre-scaled by CEXP. S^T = K·Q^T; p = exp2(s); O^T = V^T·P^T.
// grid (Ng/512, B*M); wave owns 128 q-rows (8 q-tiles) -> 8 independent
// MFMA->exp2->MFMA chains per K-tile (ILP) + 8x arithmetic per K/V load.
// Prefetch depth 2 (named A/B register sets); setprio(1) around compute.
__global__ __launch_bounds__(256, 2) void attn_kernel(
    const bf16_t* __restrict__ Q, const bf16_t* __restrict__ Kk,
    const bf16_t* __restrict__ Vt, bf16_t* __restrict__ ctx)
{
  const int t = threadIdx.x;
  const int lane = t & 63, w = t >> 6;
  const int q4 = lane >> 4, r16 = lane & 15;
  const int bm = blockIdx.y;
  const int b = bm >> 3, m = bm & 7;
  const int q0 = blockIdx.x * 512 + w * 128;

  bf16x8 qf[8];
#pragma unroll
  for (int qt = 0; qt < 8; qt++)
    qf[qt] = *(const bf16x8*)(Q + ((size_t)(b * 8192 + q0 + qt * 16 + r16) * 256 + m * 32 + q4 * 8));

  f32x4 acc[8][2] = {};
  float lsum[8] = {0.f, 0.f, 0.f, 0.f, 0.f, 0.f, 0.f, 0.f};

  const bf16_t* kbase  = Kk + (size_t)b * 512 * 256 + m * 32 + (size_t)r16 * 256 + q4 * 8;
  const bf16_t* vbase0 = Vt + (size_t)bm * 32 * 512 + ((size_t)r16 << 9) + q4 * 4;
  const bf16_t* vbase1 = vbase0 + (16 << 9);

  // prefetch slots A (k0) and B (k0+16); over-reads past k=512 land in the
  // adjacent allocated ws regions and are never consumed — safe.
  bf16x8 kfA = *(const bf16x8*)(kbase);
  bf16x4 v0A = *(const bf16x4*)(vbase0);
  bf16x4 v1A = *(const bf16x4*)(vbase1);
  bf16x8 kfB = *(const bf16x8*)(kbase + (size_t)16 * 256);
  bf16x4 v0B = *(const bf16x4*)(vbase0 + 16);
  bf16x4 v1B = *(const bf16x4*)(vbase1 + 16);

  for (int k0 = 0; k0 < 512; k0 += 32) {
    // ---- tile k0 from slot A; prefetch k0+32 into A ----
    const bf16x8 ka = kfA;
    const bf16x4 va0 = v0A, va1 = v1A;
    kfA = *(const bf16x8*)(kbase + (size_t)(k0 + 32) * 256);
    v0A = *(const bf16x4*)(vbase0 + k0 + 32);
    v1A = *(const bf16x4*)(vbase1 + k0 + 32);
    __builtin_amdgcn_s_setprio(1);
#pragma unroll
    for (int qt = 0; qt < 8; qt++) {
      f32x4 z = {};
      const f32x4 s = __builtin_amdgcn_mfma_f32_16x16x32_bf16(ka, qf[qt], z, 0, 0, 0);
      const float e0 = fexp2(s[0]), e1 = fexp2(s[1]);
      const float e2 = fexp2(s[2]), e3 = fexp2(s[3]);
      lsum[qt] += (e0 + e1) + (e2 + e3);
      const bf16x4 p = {(bf16_t)e0, (bf16_t)e1, (bf16_t)e2, (bf16_t)e3};
      acc[qt][0] = mfma16x16x16(va0, p, acc[qt][0]);
      acc[qt][1] = mfma16x16x16(va1, p, acc[qt][1]);
    }
    __builtin_amdgcn_s_setprio(0);
    // ---- tile k0+16 from slot B; prefetch k0+48 into B ----
    const bf16x8 kb = kfB;
    const bf16x4 vb0 = v0B, vb1 = v1B;
    kfB = *(const bf16x8*)(kbase + (size_t)(k0 + 48) * 256);
    v0B = *(const bf16x4*)(vbase0 + k0 + 48);
    v1B = *(const bf16x4*)(vbase1 + k0 + 48);
    __builtin_amdgcn_s_setprio(1);
#pragma unroll
    for (int qt = 0; qt < 8; qt++) {
      f32x4 z = {};
      const f32x4 s = __builtin_amdgcn_mfma_f32_16x16x32_bf16(kb, qf[qt], z, 0, 0, 0);
      const float e0 = fexp2(s[0]), e1 = fexp2(s[1]);
      const float e2 = fexp2(s[2]), e3 = fexp2(s[3]);
      lsum[qt] += (e0 + e1) + (e2 + e3);
      const bf16x4 p = {(bf16_t)e0, (bf16_t)e1, (bf16_t)e2, (bf16_t)e3};
      acc[qt][0] = mfma16x16x16(vb0, p, acc[qt][0]);
      acc[qt][1] = mfma16x16x16(vb1, p, acc[qt][1]);
    }
    __builtin_amdgcn_s_setprio(0);
  }

#pragma unroll
  for (int qt = 0; qt < 8; qt++) {
    float v = lsum[qt];
    v += __shfl_xor(v, 16, 64);
    v += __shfl_xor(v, 32, 64);
    const float inv = 1.0f / v;
    const size_t row = (size_t)b * 8192 + q0 + qt * 16 + r16;
    bf16x4 o0, o1;
#pragma unroll
    for (int rr = 0; rr < 4; rr++) {
      o0[rr] = (bf16_t)(acc[qt][0][rr] * inv);
      o1[rr] = (bf16_t)(acc[qt][1][rr] * inv);
    }
    *(bf16x4*)(ctx + row * 256 + m * 32 + q4 * 4)      = o0;
    *(bf16x4*)(ctx + row * 256 + m * 32 + 16 + q4 * 4) = o1;
  }
}

// ================= residual + LayerNorm -> gq hi/lo split ==================
__global__ __launch_bounds__(256) void ln_kernel(
    const bf16_t* __restrict__ y2, const void* __restrict__ query,
    const void* __restrict__ g, const void* __restrict__ beta,
    bf16_t* __restrict__ gqh, bf16_t* __restrict__ gql)
{
  const int isf = detect_isf(query);
  const int rowb = blockIdx.x * 4 + (threadIdx.x >> 6);
  const int lane = threadIdx.x & 63;
  const size_t base = (size_t)rowb * 256;
  const int c0 = lane * 4;
  float x[4];
  {
    const bf16x4 yv = *(const bf16x4*)(y2 + base + c0);
    if (isf) {
      const float4 qv = *(const float4*)((const float*)query + base + c0);
      x[0] = qv.x + (float)yv[0]; x[1] = qv.y + (float)yv[1];
      x[2] = qv.z + (float)yv[2]; x[3] = qv.w + (float)yv[3];
    } else {
      const bf16x4 qv = *(const bf16x4*)((const bf16_t*)query + base + c0);
#pragma unroll
      for (int k = 0; k < 4; k++) x[k] = (float)qv[k] + (float)yv[k];
    }
  }
  float s = x[0] + x[1] + x[2] + x[3];
  for (int d = 1; d < 64; d <<= 1) s += __shfl_xor(s, d, 64);
  const float mu = s * (1.0f / 256.0f);
  float vs = 0.f;
#pragma unroll
  for (int k = 0; k < 4; k++) { const float d = x[k] - mu; vs += d * d; }
  for (int d = 1; d < 64; d <<= 1) vs += __shfl_xor(vs, d, 64);
  const float rstd = rsqrtf(vs * (1.0f / 256.0f) + 1e-5f);
  float gw[4], bb[4];
  if (isf) {
    const float4 gg = *(const float4*)((const float*)g + c0);
    const float4 bv = *(const float4*)((const float*)beta + c0);
    gw[0] = gg.x; gw[1] = gg.y; gw[2] = gg.z; gw[3] = gg.w;
    bb[0] = bv.x; bb[1] = bv.y; bb[2] = bv.z; bb[3] = bv.w;
  } else {
    const bf16x4 gg = *(const bf16x4*)((const bf16_t*)g + c0);
    const bf16x4 bv = *(const bf16x4*)((const bf16_t*)beta + c0);
#pragma unroll
    for (int k = 0; k < 4; k++) { gw[k] = (float)gg[k]; bb[k] = (float)bv[k]; }
  }
  bf16x4 hi4, lo4;
#pragma unroll
  for (int k = 0; k < 4; k++) {
    const float gv = (x[k] - mu) * rstd * gw[k] + bb[k];
    const bf16_t hi = (bf16_t)gv;
    hi4[k] = hi;
    lo4[k] = (bf16_t)(gv - (float)hi);
  }
  *(bf16x4*)(gqh + base + c0) = hi4;
  *(bf16x4*)(gql + base + c0) = lo4;
}

// ===== fused offs/attw GEMM: ysamp = gqh*(Wh+Wl)^T + gql*Wh^T + bias =======
// epilogue scatters into per-(b,m) packed layout: ys2[(bm*8192+q)*16+inner]
__global__ __launch_bounds__(256) void gemm_offs(
    const bf16_t* __restrict__ Ahg, const bf16_t* __restrict__ Alg,
    const bf16_t* __restrict__ Whg, const bf16_t* __restrict__ Wlg,
    const bf16_t* __restrict__ bias, float* __restrict__ Cout)
{
  __shared__ __align__(16) bf16_t Ah[128 * 64];
  __shared__ __align__(16) bf16_t Al[128 * 64];
  __shared__ __align__(16) bf16_t Wh[128 * 64];
  __shared__ __align__(16) bf16_t Wl[128 * 64];
  const int t    = threadIdx.x;
  const int lane = t & 63;
  const int w    = t >> 6;
  const int wm   = (w & 1) * 64;
  const int wn   = (w >> 1) * 64;
  const int q4   = lane >> 4;
  const int r16  = lane & 15;
  const int tm   = blockIdx.x * 128;

  f32x4 acc[4][4] = {};
  const int srow = t >> 1;
  const int skb  = (t & 1) * 32;

  for (int kt = 0; kt < 256; kt += 64) {
    __syncthreads();
    {
      const uint4* g0 = (const uint4*)(Ahg + (size_t)(tm + srow) * 256 + kt + skb);
      uint4* l0 = (uint4*)(Ah + srow * 64 + skb);
      l0[0] = g0[0]; l0[1] = g0[1]; l0[2] = g0[2]; l0[3] = g0[3];
      const uint4* g1 = (const uint4*)(Alg + (size_t)(tm + srow) * 256 + kt + skb);
      uint4* l1 = (uint4*)(Al + srow * 64 + skb);
      l1[0] = g1[0]; l1[1] = g1[1]; l1[2] = g1[2]; l1[3] = g1[3];
      const uint4* g2 = (const uint4*)(Whg + (size_t)srow * 256 + kt + skb);
      uint4* l2 = (uint4*)(Wh + srow * 64 + skb);
      l2[0] = g2[0]; l2[1] = g2[1]; l2[2] = g2[2]; l2[3] = g2[3];
      const uint4* g3 = (const uint4*)(Wlg + (size_t)srow * 256 + kt + skb);
      uint4* l3 = (uint4*)(Wl + srow * 64 + skb);
      l3[0] = g3[0]; l3[1] = g3[1]; l3[2] = g3[2]; l3[3] = g3[3];
    }
    __syncthreads();
#pragma unroll
    for (int ks = 0; ks < 64; ks += 32) {
      bf16x8 ah[4], al[4], bh[4], bl[4];
#pragma unroll
      for (int i = 0; i < 4; i++) {
        ah[i] = *(const bf16x8*)(Ah + (wm + 16 * i + r16) * 64 + ks + q4 * 8);
        al[i] = *(const bf16x8*)(Al + (wm + 16 * i + r16) * 64 + ks + q4 * 8);
      }
#pragma unroll
      for (int j = 0; j < 4; j++) {
        bh[j] = *(const bf16x8*)(Wh + (wn + 16 * j + r16) * 64 + ks + q4 * 8);
        bl[j] = *(const bf16x8*)(Wl + (wn + 16 * j + r16) * 64 + ks + q4 * 8);
      }
#pragma unroll
      for (int i = 0; i < 4; i++)
#pragma unroll
        for (int j = 0; j < 4; j++) {
          f32x4 a = acc[i][j];
          a = __builtin_amdgcn_mfma_f32_16x16x32_bf16(al[i], bh[j], a, 0, 0, 0);
          a = __builtin_amdgcn_mfma_f32_16x16x32_bf16(ah[i], bl[j], a, 0, 0, 0);
          a = __builtin_amdgcn_mfma_f32_16x16x32_bf16(ah[i], bh[j], a, 0, 0, 0);
          acc[i][j] = a;
        }
    }
  }

#pragma unroll
  for (int j = 0; j < 4; j++) {
    const int col = wn + 16 * j + r16;
    const float bv = (float)bias[col];
    // remap col -> (m, inner); cols >=96 are dead (zero weights+bias)
    const int live  = (col < 96) ? 1 : 0;
    const int moff  = (col < 64) ? (col >> 3) : ((col - 64) >> 2);
    const int inner = (col < 64) ? (col & 7) : (8 + (col & 3));
#pragma unroll
    for (int i = 0; i < 4; i++) {
      const int row0 = tm + wm + 16 * i + q4 * 4;
#pragma unroll
      for (int rr = 0; rr < 4; rr++) {
        if (live) {
          const int row = row0 + rr;
          const int bq = row >> 13, q = row & 8191;
          Cout[(((size_t)(bq * 8 + moff) << 13) + q) * 16 + inner] = acc[i][j][rr] + bv;
        }
      }
    }
  }
}

// ===================== deformable bilinear sampler =========================
// Channel-split: 2 threads/query (hf = channel half), grid 2048 -> 8 waves/
// SIMD ceiling. 1D swizzle keeps bm%8 == XCD. ys2 = packed 64B/query layout.
__global__ __launch_bounds__(256) void sampler(
    const float* __restrict__ ys2, const void* __restrict__ refp,
    const bf16_t* __restrict__ vperm, bf16_t* __restrict__ outs,
    const void* __restrict__ qdet)
{
  const int isf = detect_isf(qdet);
  const int t = threadIdx.x;
  const int wg = blockIdx.x;
  const int bm  = (wg & 7) + ((wg >> 9) << 3);  // XCD = wg%8 = bm%8
  const int mid = (wg >> 3) & 63;
  const int qt  = mid >> 1;
  const int hf  = mid & 1;                      // channel half
  const int b = bm >> 3, m = bm & 7;
  const int qq = qt * 256 + t;
  const size_t row = (size_t)b * 8192 + qq;
  const float* y16 = ys2 + (((size_t)bm << 13) + qq) * 16;
  const float rx = ldf(refp, row * 2 + 0, isf);
  const float ry = ldf(refp, row * 2 + 1, isf);

  const float4 off01 = *(const float4*)(y16 + 0);
  const float4 off23 = *(const float4*)(y16 + 4);
  const float4 lg    = *(const float4*)(y16 + 8);

  const float mx = fmaxf(fmaxf(lg.x, lg.y), fmaxf(lg.z, lg.w));
  const float e0 = __expf(lg.x - mx), e1 = __expf(lg.y - mx);
  const float e2 = __expf(lg.z - mx), e3 = __expf(lg.w - mx);
  const float inv = 1.0f / (e0 + e1 + e2 + e3);
  const float aw[4] = {e0 * inv, e1 * inv, e2 * inv, e3 * inv};
  const float ox[4] = {off01.x, off01.z, off23.x, off23.z};
  const float oy[4] = {off01.y, off01.w, off23.y, off23.w};

  float acc[16];
#pragma unroll
  for (int ch = 0; ch < 16; ch++) acc[ch] = 0.0f;

  const bf16_t* vbase = vperm + (size_t)bm * (128 * 128 * 32) + hf * 16;

  for (int p = 0; p < 4; p++) {
    const float gx = (rx + ox[p]) * 128.0f - 0.5f;
    const float gy = (ry + oy[p]) * 128.0f - 0.5f;
    const float x0f = floorf(gx), y0f = floorf(gy);
    const int x0 = (int)x0f, y0i = (int)y0f;
    const float wx1 = gx - x0f, wx0 = 1.0f - wx1;
    const float wy1 = gy - y0f, wy0 = 1.0f - wy1;
    const float a = aw[p];
    for (int cy = 0; cy < 2; cy++) {
      const int yy = y0i + cy;
      if (yy < 0 || yy >= 128) continue;
      const float wy = cy ? wy1 : wy0;
      for (int cx = 0; cx < 2; cx++) {
        const int xx = x0 + cx;
        if (xx < 0 || xx >= 128) continue;
        const float wgt = a * wy * (cx ? wx1 : wx0);
        const bf16x8* src8 = (const bf16x8*)(vbase + ((size_t)yy * 128 + xx) * 32);
        const bf16x8 d0 = src8[0];
        const bf16x8 d1 = src8[1];
#pragma unroll
        for (int e = 0; e < 8; e++) {
          acc[e]     += wgt * (float)d0[e];
          acc[8 + e] += wgt * (float)d1[e];
        }
      }
    }
  }

  const size_t obase = (size_t)b * 8192;
#pragma unroll
  for (int ch = 0; ch < 16; ch++) {
    const int chg = hf * 16 + ch;
    const size_t orow = obase + (size_t)(chg * 8 + m) * 32 + qt;
    outs[orow * 256 + t] = (bf16_t)acc[ch];
  }
}

// ===========================================================================
extern "C" void kernel_launch(void* const* d_in, const int* in_sizes, int n_in,
                              void* d_out, int out_size, void* d_ws, size_t ws_size,
                              hipStream_t stream) {
  const void* query = d_in[0];
  const void* value = d_in[1];
  const void* refp  = d_in[2];
  const void* trajp = d_in[3];
  const void* in_w  = d_in[4];
  const void* in_b  = d_in[5];
  const void* mow   = d_in[6];
  const void* mob   = d_in[7];
  const void* lng   = d_in[8];
  const void* lnb   = d_in[9];
  const void* tw    = d_in[10];
  const void* tb    = d_in[11];
  const void* ow    = d_in[12];
  const void* ob    = d_in[13];
  const void* aww   = d_in[14];
  const void* awb   = d_in[15];
  const void* outw  = d_in[16];
  const void* outb  = d_in[17];

  char* base = (char*)d_ws;
  float*  ysamp = (float*)(base);
  bf16_t* qout  = (bf16_t*)(base + 16777216);
  bf16_t* ctx   = (bf16_t*)(base + 33554432);
  bf16_t* y2    = (bf16_t*)(base + 50331648);
  bf16_t* tf_ws = (bf16_t*)(base + 67108864);
  bf16_t* k_ws  = (bf16_t*)(base + 68157440);
  bf16_t* vt_g  = (bf16_t*)(base + 69206016);
  bf16_t* blob  = (bf16_t*)(base + 70254592);

  bf16_t* gqh   = qout;
  bf16_t* gql   = ctx;
  // vperm de-aliased: dedicated 32MB at +128MiB (ws is 256MiB per the
  // harness fill size) -> transpose can run inside prep_all at t=0.
  bf16_t* vperm = (bf16_t*)(base + 134217728);
  bf16_t* outs  = y2;

  bf16_t* inw_bf  = blob;
  bf16_t* inb_bf  = blob + 196608;
  bf16_t* mow_bf  = blob + 197376;
  bf16_t* mob_bf  = blob + 262912;
  bf16_t* outw_bf = blob + 263168;
  bf16_t* outb_bf = blob + 328704;
  bf16_t* wph     = blob + 328960;
  bf16_t* wpl     = blob + 361728;
  bf16_t* bpad    = blob + 394496;

  prep_all<<<dim3(6594), dim3(256), 0, stream>>>(
      query, in_w, in_b, mow, mob, outw, outb, trajp, tw, tb,
      ow, aww, ob, awb, blob, tf_ws, wph, wpl, bpad, value, vperm);
  gemm_qkv<<<dim3(576), dim3(256), 0, stream>>>(
      query, inw_bf, inb_bf, qout,
      tf_ws, inw_bf + 65536, inb_bf + 256, k_ws, vt_g, CEXP, query);
  attn_kernel<<<dim3(16, 32), dim3(256), 0, stream>>>(qout, k_ws, vt_g, ctx);
  gemm_async<<<dim3(256, 2), dim3(256), 0, stream>>>(
      ctx, mow_bf, mob_bf, (void*)y2, nullptr, 256, 256, 0, 1.0f, query);
  ln_kernel<<<dim3(8192), dim3(256), 0, stream>>>(y2, query, lng, lnb, gqh, gql);
  gemm_offs<<<dim3(256, 1), dim3(256), 0, stream>>>(gqh, gql, wph, wpl, bpad, ysamp);
  sampler<<<dim3(2048), dim3(256), 0, stream>>>(ysamp, refp, vperm, outs, query);
  gemm_async<<<dim3(256, 2), dim3(256), 0, stream>>>(
      outs, outw_bf, outb_bf, d_out, nullptr, 256, 256, 3, 1.0f, query);
}

// Round 8
// 316.785 us; speedup vs baseline: 1.0980x; 1.0528x over previous
//
#include <hip/hip_runtime.h>
#include <hip/hip_bf16.h>
#include <stdint.h>

typedef __bf16 bf16_t;
typedef __bf16 bf16x8 __attribute__((ext_vector_type(8)));
typedef __bf16 bf16x4 __attribute__((ext_vector_type(4)));
typedef float f32x4 __attribute__((ext_vector_type(4)));

// Shapes: B=4 Ng=8192 C=256 H=W=128 Nt=512 M=8 P=4 Ch=32
#define CEXP 0.25506807186679906f  // (1/sqrt(32)) * log2(e), folded into K

__device__ __forceinline__ float ldf(const void* p, size_t i, int isf) {
  return isf ? ((const float*)p)[i] : (float)((const bf16_t*)p)[i];
}

// per-wave dtype detect on query[0:128 elems] — deterministic everywhere
__device__ __forceinline__ int detect_isf(const void* q) {
  const uint16_t* u = (const uint16_t*)q;
  const int lane = threadIdx.x & 63;
  const uint16_t v = u[2 * lane];
  const int e = (v >> 7) & 0xFF;
  const int weird = (e >= 0x86 || (v != 0 && e <= 0x65)) ? 1 : 0;
  return (__popcll(__ballot(weird)) >= 16) ? 1 : 0;
}

__device__ __forceinline__ float fexp2(float x) {
#if __has_builtin(__builtin_amdgcn_exp2f)
  return __builtin_amdgcn_exp2f(x);
#else
  return exp2f(x);
#endif
}

// 16x16x16 bf16 MFMA: C-layout of a 16x16 tile == B-layout of this shape.
__device__ __forceinline__ f32x4 mfma16x16x16(bf16x4 a, bf16x4 b, f32x4 c) {
#if __has_builtin(__builtin_amdgcn_mfma_f32_16x16x16_bf16)
  return __builtin_amdgcn_mfma_f32_16x16x16_bf16(a, b, c, 0, 0, 0);
#else
  typedef short s16x4 __attribute__((ext_vector_type(4)));
  return __builtin_amdgcn_mfma_f32_16x16x16bf16_1k(
      __builtin_bit_cast(s16x4, a), __builtin_bit_cast(s16x4, b), c, 0, 0, 0);
#endif
}

// async global->LDS, 16B per lane
__device__ __forceinline__ void stage16(const bf16_t* g, bf16_t* l) {
  __builtin_amdgcn_global_load_lds((const __attribute__((address_space(1))) void*)g,
                                   (__attribute__((address_space(3))) void*)l, 16, 0, 0);
}

// == merged prep: weights->bf16 | tf proj | wpad hi/lo | value transpose ====
__global__ __launch_bounds__(256) void prep_all(
    const void* __restrict__ query,
    const void* in_w, const void* in_b, const void* mow, const void* mob,
    const void* outw, const void* outb,
    const void* trajp, const void* tw, const void* tb,
    const void* offs_w, const void* attw_w, const void* offs_b, const void* attw_b,
    bf16_t* __restrict__ blob, bf16_t* __restrict__ tf,
    bf16_t* __restrict__ Wph, bf16_t* __restrict__ Wpl, bf16_t* __restrict__ bp,
    const void* __restrict__ V, bf16_t* __restrict__ Vp)
{
  __shared__ __align__(16) bf16_t tile[32][136];
  const int isf = detect_isf(query);
  const int bid = blockIdx.x;
  if (bid < 322) {
    const int g = (bid * 256 + threadIdx.x) * 4;
    if (g >= 328960) return;
    const void* src; size_t off;
    if      (g < 196608) { src = in_w; off = g; }
    else if (g < 197376) { src = in_b; off = g - 196608; }
    else if (g < 262912) { src = mow;  off = g - 197376; }
    else if (g < 263168) { src = mob;  off = g - 262912; }
    else if (g < 328704) { src = outw; off = g - 263168; }
    else                 { src = outb; off = g - 328704; }
#pragma unroll
    for (int k = 0; k < 4; k++) blob[g + k] = (bf16_t)ldf(src, off + k, isf);
  } else if (bid < 322 + 2048) {
    const int rowb = bid - 322;
    const int c = threadIdx.x;
    const float x = ldf(trajp, rowb * 2 + 0, isf);
    const float y = ldf(trajp, rowb * 2 + 1, isf);
    const float v = x * ldf(tw, c * 2 + 0, isf) + y * ldf(tw, c * 2 + 1, isf) + ldf(tb, c, isf);
    tf[(size_t)rowb * 256 + c] = (bf16_t)v;
  } else if (bid < 2498) {
    const int idx = (bid - 2370) * 256 + threadIdx.x;
    const int rowp = idx >> 8, c = idx & 255;
    float v = 0.0f;
    if (rowp < 64)      v = ldf(offs_w, rowp * 256 + c, isf);
    else if (rowp < 96) v = ldf(attw_w, (rowp - 64) * 256 + c, isf);
    const bf16_t hi = (bf16_t)v;
    Wph[idx] = hi;
    Wpl[idx] = (bf16_t)(v - (float)hi);
    if (idx < 128) {
      float bv = 0.0f;
      if (idx < 64)      bv = ldf(offs_b, idx, isf);
      else if (idx < 96) bv = ldf(attw_b, idx - 64, isf);
      bp[idx] = (bf16_t)bv;
    }
  } else {
    // ---- value transpose (B,C,H,W) -> (B,M,H,W,Ch), vectorized ----
    const int vb = bid - 2498;
    const int h = vb & 127;
    const int bm = vb >> 7;
    const int b = bm >> 3, mm = bm & 7;
    const int t = threadIdx.x;
    const int ch  = t >> 3;
    const int ww0 = (t & 7) * 16;
    const size_t ibase = (((size_t)b * 256 + mm * 32 + ch) * 128 + h) * 128 + ww0;
    if (isf) {
      const float4* src = (const float4*)((const float*)V + ibase);
      bf16x8 h0, h1;
#pragma unroll
      for (int k = 0; k < 2; k++) {
        const float4 u0 = src[k * 2], u1 = src[k * 2 + 1];
        bf16x8 hh = {(bf16_t)u0.x, (bf16_t)u0.y, (bf16_t)u0.z, (bf16_t)u0.w,
                     (bf16_t)u1.x, (bf16_t)u1.y, (bf16_t)u1.z, (bf16_t)u1.w};
        if (k == 0) h0 = hh; else h1 = hh;
      }
      *(bf16x8*)(&tile[ch][ww0])     = h0;
      *(bf16x8*)(&tile[ch][ww0 + 8]) = h1;
    } else {
      const bf16x8* src = (const bf16x8*)((const bf16_t*)V + ibase);
      *(bf16x8*)(&tile[ch][ww0])     = src[0];
      *(bf16x8*)(&tile[ch][ww0 + 8]) = src[1];
    }
    __syncthreads();
    const size_t base = ((size_t)bm * 128 + h) * 4096;
    const int ww = t >> 1;
    const int c0 = (t & 1) * 16;
    bf16x8 o0, o1;
#pragma unroll
    for (int e = 0; e < 8; e++) { o0[e] = tile[c0 + e][ww]; o1[e] = tile[c0 + 8 + e][ww]; }
    *(bf16x8*)(Vp + base + ww * 32 + c0)     = o0;
    *(bf16x8*)(Vp + base + ww * 32 + c0 + 8) = o1;
  }
}

// ============== async-staged bf16 GEMM: C = A@W^T + bias ===================
// mode 3: dtype-of-query store (final output GEMM)
#define TM 128
#define TN 128
#define TKK 64

__global__ __launch_bounds__(256) void gemm_async(
    const bf16_t* __restrict__ A, const bf16_t* __restrict__ W,
    const bf16_t* __restrict__ bias, void* __restrict__ Cout,
    void* __restrict__ Cout2, int Ndim, int Kdim, int mode, float kscale,
    const void* __restrict__ qdet)
{
  __shared__ __align__(16) bf16_t As[TM * TKK];
  __shared__ __align__(16) bf16_t Ws[TN * TKK];
  const int t    = threadIdx.x;
  const int lane = t & 63;
  const int w    = t >> 6;
  const int wm   = (w & 1) * 64;
  const int wn   = (w >> 1) * 64;
  const int q4   = lane >> 4;
  const int r16  = lane & 15;
  const int tm   = blockIdx.x * TM;
  const int tn   = blockIdx.y * TN;

  f32x4 acc[4][4] = {};

  for (int kt = 0; kt < Kdim; kt += TKK) {
    __syncthreads();
#pragma unroll
    for (int r = 0; r < 4; r++) {
      const int L = w * 256 + r * 64 + lane;
      const int R = L >> 3, c = (L & 7) * 8;
      stage16(A + (size_t)(tm + R) * Kdim + kt + c, As + L * 8);
      stage16(W + (size_t)(tn + R) * Kdim + kt + c, Ws + L * 8);
    }
    __syncthreads();
#pragma unroll
    for (int ks = 0; ks < TKK; ks += 32) {
      bf16x8 af[4], bfm[4];
#pragma unroll
      for (int i = 0; i < 4; i++)
        af[i] = *(const bf16x8*)(As + (wm + 16 * i + r16) * TKK + ks + q4 * 8);
#pragma unroll
      for (int j = 0; j < 4; j++)
        bfm[j] = *(const bf16x8*)(Ws + (wn + 16 * j + r16) * TKK + ks + q4 * 8);
#pragma unroll
      for (int i = 0; i < 4; i++)
#pragma unroll
        for (int j = 0; j < 4; j++)
          acc[i][j] = __builtin_amdgcn_mfma_f32_16x16x32_bf16(af[i], bfm[j], acc[i][j], 0, 0, 0);
    }
  }

  const int isf = (mode == 3) ? detect_isf(qdet) : 1;
#pragma unroll
  for (int j = 0; j < 4; j++) {
    const int col = tn + wn + 16 * j + r16;
    const float bv = (float)bias[col];
#pragma unroll
    for (int i = 0; i < 4; i++) {
      const int row0 = tm + wm + 16 * i + q4 * 4;
#pragma unroll
      for (int rr = 0; rr < 4; rr++) {
        const float v = acc[i][j][rr] + bv;
        const size_t off = (size_t)(row0 + rr) * Ndim + col;
        if (mode == 0) {
          ((bf16_t*)Cout)[off] = (bf16_t)v;
        } else {
          if (isf) ((float*)Cout)[off] = v; else ((bf16_t*)Cout)[off] = (bf16_t)v;
        }
      }
    }
  }
}

// ========== merged Q-proj (f32a path) + K/V-proj (mode-6 path) =============
__global__ __launch_bounds__(256) void gemm_qkv(
    const void* __restrict__ Araw, const bf16_t* __restrict__ Wq,
    const bf16_t* __restrict__ bq, bf16_t* __restrict__ Cq,
    const bf16_t* __restrict__ Atf, const bf16_t* __restrict__ Wkv,
    const bf16_t* __restrict__ bkv, bf16_t* __restrict__ Kout,
    bf16_t* __restrict__ Vtout, float kscale, const void* __restrict__ qdet)
{
  __shared__ __align__(16) bf16_t As[TM * TKK];
  __shared__ __align__(16) bf16_t Ws[TN * TKK];
  const int t    = threadIdx.x;
  const int lane = t & 63;
  const int w    = t >> 6;
  const int wm   = (w & 1) * 64;
  const int wn   = (w >> 1) * 64;
  const int q4   = lane >> 4;
  const int r16  = lane & 15;
  const int blk  = blockIdx.x;

  f32x4 acc[4][4] = {};

  if (blk < 512) {
    const int tm = (blk >> 1) * TM;
    const int tn = (blk & 1) * TN;
    const int aisf = detect_isf(qdet);
    const int srow = t >> 1;
    const int skb  = (t & 1) * 32;

    for (int kt = 0; kt < 256; kt += TKK) {
      __syncthreads();
      if (aisf) {
        const float4* ga = (const float4*)((const float*)Araw + (size_t)(tm + srow) * 256 + kt + skb);
#pragma unroll
        for (int kk = 0; kk < 8; kk++) {
          const float4 u = ga[kk];
          bf16x4 h = {(bf16_t)u.x, (bf16_t)u.y, (bf16_t)u.z, (bf16_t)u.w};
          *(bf16x4*)(As + srow * TKK + skb + kk * 4) = h;
        }
      } else {
        const uint4* ga = (const uint4*)((const bf16_t*)Araw + (size_t)(tm + srow) * 256 + kt + skb);
        uint4* la = (uint4*)(As + srow * TKK + skb);
        la[0] = ga[0]; la[1] = ga[1]; la[2] = ga[2]; la[3] = ga[3];
      }
      {
        const uint4* gw = (const uint4*)(Wq + (size_t)(tn + srow) * 256 + kt + skb);
        uint4* lw = (uint4*)(Ws + srow * TKK + skb);
        lw[0] = gw[0]; lw[1] = gw[1]; lw[2] = gw[2]; lw[3] = gw[3];
      }
      __syncthreads();
#pragma unroll
      for (int ks = 0; ks < TKK; ks += 32) {
        bf16x8 af[4], bfm[4];
#pragma unroll
        for (int i = 0; i < 4; i++)
          af[i] = *(const bf16x8*)(As + (wm + 16 * i + r16) * TKK + ks + q4 * 8);
#pragma unroll
        for (int j = 0; j < 4; j++)
          bfm[j] = *(const bf16x8*)(Ws + (wn + 16 * j + r16) * TKK + ks + q4 * 8);
#pragma unroll
        for (int i = 0; i < 4; i++)
#pragma unroll
          for (int j = 0; j < 4; j++)
            acc[i][j] = __builtin_amdgcn_mfma_f32_16x16x32_bf16(af[i], bfm[j], acc[i][j], 0, 0, 0);
      }
    }

#pragma unroll
    for (int j = 0; j < 4; j++) {
      const int col = tn + wn + 16 * j + r16;
      const float bv = (float)bq[col];
#pragma unroll
      for (int i = 0; i < 4; i++) {
        const int row0 = tm + wm + 16 * i + q4 * 4;
#pragma unroll
        for (int rr = 0; rr < 4; rr++)
          Cq[(size_t)(row0 + rr) * 256 + col] = (bf16_t)(acc[i][j][rr] + bv);
      }
    }
  } else {
    const int k = blk - 512;
    const int tm = (k & 15) * TM;
    const int tn = (k >> 4) * TN;

    for (int kt = 0; kt < 256; kt += TKK) {
      __syncthreads();
#pragma unroll
      for (int r = 0; r < 4; r++) {
        const int L = w * 256 + r * 64 + lane;
        const int R = L >> 3, c = (L & 7) * 8;
        stage16(Atf + (size_t)(tm + R) * 256 + kt + c, As + L * 8);
        stage16(Wkv + (size_t)(tn + R) * 256 + kt + c, Ws + L * 8);
      }
      __syncthreads();
#pragma unroll
      for (int ks = 0; ks < TKK; ks += 32) {
        bf16x8 af[4], bfm[4];
#pragma unroll
        for (int i = 0; i < 4; i++)
          af[i] = *(const bf16x8*)(As + (wm + 16 * i + r16) * TKK + ks + q4 * 8);
#pragma unroll
        for (int j = 0; j < 4; j++)
          bfm[j] = *(const bf16x8*)(Ws + (wn + 16 * j + r16) * TKK + ks + q4 * 8);
#pragma unroll
        for (int i = 0; i < 4; i++)
#pragma unroll
          for (int j = 0; j < 4; j++)
            acc[i][j] = __builtin_amdgcn_mfma_f32_16x16x32_bf16(af[i], bfm[j], acc[i][j], 0, 0, 0);
      }
    }

#pragma unroll
    for (int j = 0; j < 4; j++) {
      const int col = tn + wn + 16 * j + r16;
      const float bv = (float)bkv[col];
#pragma unroll
      for (int i = 0; i < 4; i++) {
        const int row0 = tm + wm + 16 * i + q4 * 4;
#pragma unroll
        for (int rr = 0; rr < 4; rr++) {
          const float v = acc[i][j][rr] + bv;
          const int rowg = row0 + rr;
          if (col < 256) {
            Kout[(size_t)rowg * 256 + col] = (bf16_t)(v * kscale);
          } else {
            const int bb = rowg >> 9, tt = rowg & 511;
            const int c2 = col - 256;
            const int mm = c2 >> 5, ch = c2 & 31;
            Vtout[(((size_t)(bb * 8 + mm) * 32 + ch) << 9) + tt] = (bf16_t)v;
          }
        }
      }
    }
  }
}

// ==================== attention: LDS-free, per-head ========================
__global__ __launch_bounds__(256, 2) void attn_kernel(
    const bf16_t* __restrict__ Q, const bf16_t* __restrict__ Kk,
    const bf16_t* __restrict__ Vt, bf16_t* __restrict__ ctx)
{
  const int t = threadIdx.x;
  const int lane = t & 63, w = t >> 6;
  const int q4 = lane >> 4, r16 = lane & 15;
  const int bm = blockIdx.y;
  const int b = bm >> 3, m = bm & 7;
  const int q0 = blockIdx.x * 512 + w * 128;

  bf16x8 qf[8];
#pragma unroll
  for (int qt = 0; qt < 8; qt++)
    qf[qt] = *(const bf16x8*)(Q + ((size_t)(b * 8192 + q0 + qt * 16 + r16) * 256 + m * 32 + q4 * 8));

  f32x4 acc[8][2] = {};
  float lsum[8] = {0.f, 0.f, 0.f, 0.f, 0.f, 0.f, 0.f, 0.f};

  const bf16_t* kbase  = Kk + (size_t)b * 512 * 256 + m * 32 + (size_t)r16 * 256 + q4 * 8;
  const bf16_t* vbase0 = Vt + (size_t)bm * 32 * 512 + ((size_t)r16 << 9) + q4 * 4;
  const bf16_t* vbase1 = vbase0 + (16 << 9);

  bf16x8 kfA = *(const bf16x8*)(kbase);
  bf16x4 v0A = *(const bf16x4*)(vbase0);
  bf16x4 v1A = *(const bf16x4*)(vbase1);
  bf16x8 kfB = *(const bf16x8*)(kbase + (size_t)16 * 256);
  bf16x4 v0B = *(const bf16x4*)(vbase0 + 16);
  bf16x4 v1B = *(const bf16x4*)(vbase1 + 16);

  for (int k0 = 0; k0 < 512; k0 += 32) {
    const bf16x8 ka = kfA;
    const bf16x4 va0 = v0A, va1 = v1A;
    kfA = *(const bf16x8*)(kbase + (size_t)(k0 + 32) * 256);
    v0A = *(const bf16x4*)(vbase0 + k0 + 32);
    v1A = *(const bf16x4*)(vbase1 + k0 + 32);
    __builtin_amdgcn_s_setprio(1);
#pragma unroll
    for (int qt = 0; qt < 8; qt++) {
      f32x4 z = {};
      const f32x4 s = __builtin_amdgcn_mfma_f32_16x16x32_bf16(ka, qf[qt], z, 0, 0, 0);
      const float e0 = fexp2(s[0]), e1 = fexp2(s[1]);
      const float e2 = fexp2(s[2]), e3 = fexp2(s[3]);
      lsum[qt] += (e0 + e1) + (e2 + e3);
      const bf16x4 p = {(bf16_t)e0, (bf16_t)e1, (bf16_t)e2, (bf16_t)e3};
      acc[qt][0] = mfma16x16x16(va0, p, acc[qt][0]);
      acc[qt][1] = mfma16x16x16(va1, p, acc[qt][1]);
    }
    __builtin_amdgcn_s_setprio(0);
    const bf16x8 kb = kfB;
    const bf16x4 vb0 = v0B, vb1 = v1B;
    kfB = *(const bf16x8*)(kbase + (size_t)(k0 + 48) * 256);
    v0B = *(const bf16x4*)(vbase0 + k0 + 48);
    v1B = *(const bf16x4*)(vbase1 + k0 + 48);
    __builtin_amdgcn_s_setprio(1);
#pragma unroll
    for (int qt = 0; qt < 8; qt++) {
      f32x4 z = {};
      const f32x4 s = __builtin_amdgcn_mfma_f32_16x16x32_bf16(kb, qf[qt], z, 0, 0, 0);
      const float e0 = fexp2(s[0]), e1 = fexp2(s[1]);
      const float e2 = fexp2(s[2]), e3 = fexp2(s[3]);
      lsum[qt] += (e0 + e1) + (e2 + e3);
      const bf16x4 p = {(bf16_t)e0, (bf16_t)e1, (bf16_t)e2, (bf16_t)e3};
      acc[qt][0] = mfma16x16x16(vb0, p, acc[qt][0]);
      acc[qt][1] = mfma16x16x16(vb1, p, acc[qt][1]);
    }
    __builtin_amdgcn_s_setprio(0);
  }

#pragma unroll
  for (int qt = 0; qt < 8; qt++) {
    float v = lsum[qt];
    v += __shfl_xor(v, 16, 64);
    v += __shfl_xor(v, 32, 64);
    const float inv = 1.0f / v;
    const size_t row = (size_t)b * 8192 + q0 + qt * 16 + r16;
    bf16x4 o0, o1;
#pragma unroll
    for (int rr = 0; rr < 4; rr++) {
      o0[rr] = (bf16_t)(acc[qt][0][rr] * inv);
      o1[rr] = (bf16_t)(acc[qt][1][rr] * inv);
    }
    *(bf16x4*)(ctx + row * 256 + m * 32 + q4 * 4)      = o0;
    *(bf16x4*)(ctx + row * 256 + m * 32 + 16 + q4 * 4) = o1;
  }
}

// ===== fused: y = ctx@mow^T + mob + query -> LayerNorm -> offs/attw GEMM ====
// 256 blocks x 512 threads (8 waves). Block owns 128 rows x ALL 256 cols.
// Eliminates y2/gqh/gql global round-trips (~100MB) and 2 launches.
// Phase 1: GEMM (TM=128, TN=256, async-staged), bias+residual into acc.
// Phase 2: row LN — shfl over r16 lanes (64 cols/wave) + 4KB LDS cross-wave.
// Phase 3: gq hi/lo split in REGISTERS -> per-64-col-chunk LDS staging ->
//          3-MFMA hi/lo offs GEMM (identical math to old gemm_offs) ->
//          packed ysamp epilogue.
__global__ __launch_bounds__(512) void gemm_mlo(
    const bf16_t* __restrict__ A, const bf16_t* __restrict__ W,
    const bf16_t* __restrict__ bias, const void* __restrict__ query,
    const void* __restrict__ lng, const void* __restrict__ lnb,
    const bf16_t* __restrict__ Whg, const bf16_t* __restrict__ Wlg,
    const bf16_t* __restrict__ bpad, float* __restrict__ Cout)
{
  __shared__ __align__(16) char smem[65536];
  __shared__ float redsum[4][128];
  __shared__ float redsq[4][128];
  bf16_t* As = (bf16_t*)smem;              // 128x64 = 16KB
  bf16_t* Ws = (bf16_t*)(smem + 16384);    // 256x64 = 32KB
  bf16_t* Ah = (bf16_t*)smem;              // offs phase: 128x64 = 16KB
  bf16_t* Al = (bf16_t*)(smem + 16384);
  bf16_t* Wh = (bf16_t*)(smem + 32768);
  bf16_t* Wl = (bf16_t*)(smem + 49152);

  const int t    = threadIdx.x;
  const int lane = t & 63;
  const int w    = t >> 6;           // 0..7
  const int wm   = (w & 1) * 64;
  const int wn   = (w >> 1) * 64;    // 0,64,128,192
  const int q4   = lane >> 4;
  const int r16  = lane & 15;
  const int R0   = blockIdx.x * 128;
  const int isf  = detect_isf(query);

  f32x4 acc[4][4] = {};

  // ---------------- phase 1: main GEMM (K=256) ----------------
  for (int kt = 0; kt < 256; kt += 64) {
    __syncthreads();
#pragma unroll
    for (int r = 0; r < 2; r++) {
      const int L = r * 512 + t;
      const int R = L >> 3, c = (L & 7) * 8;
      stage16(A + (size_t)(R0 + R) * 256 + kt + c, As + L * 8);
    }
#pragma unroll
    for (int r = 0; r < 4; r++) {
      const int L = r * 512 + t;
      const int R = L >> 3, c = (L & 7) * 8;
      stage16(W + (size_t)R * 256 + kt + c, Ws + L * 8);
    }
    __syncthreads();
#pragma unroll
    for (int ks = 0; ks < 64; ks += 32) {
      bf16x8 af[4], bfm[4];
#pragma unroll
      for (int i = 0; i < 4; i++)
        af[i] = *(const bf16x8*)(As + (wm + 16 * i + r16) * 64 + ks + q4 * 8);
#pragma unroll
      for (int j = 0; j < 4; j++)
        bfm[j] = *(const bf16x8*)(Ws + (wn + 16 * j + r16) * 64 + ks + q4 * 8);
#pragma unroll
      for (int i = 0; i < 4; i++)
#pragma unroll
        for (int j = 0; j < 4; j++)
          acc[i][j] = __builtin_amdgcn_mfma_f32_16x16x32_bf16(af[i], bfm[j], acc[i][j], 0, 0, 0);
    }
  }

  // ---------------- bias + residual ----------------
#pragma unroll
  for (int j = 0; j < 4; j++) {
    const int col = wn + 16 * j + r16;
    const float bv = (float)bias[col];
#pragma unroll
    for (int i = 0; i < 4; i++) {
#pragma unroll
      for (int rr = 0; rr < 4; rr++) {
        const int grow = R0 + wm + 16 * i + q4 * 4 + rr;
        acc[i][j][rr] += bv + ldf(query, (size_t)grow * 256 + col, isf);
      }
    }
  }

  // ---------------- phase 2: LayerNorm ----------------
  // per-(i,rr) partial over this thread's 4 cols, reduce over r16 lanes
  // (covers wave's 64 cols), cross-wave via LDS (4 col-groups).
#pragma unroll
  for (int i = 0; i < 4; i++)
#pragma unroll
    for (int rr = 0; rr < 4; rr++) {
      float s  = acc[i][0][rr] + acc[i][1][rr] + acc[i][2][rr] + acc[i][3][rr];
      float sq = acc[i][0][rr] * acc[i][0][rr] + acc[i][1][rr] * acc[i][1][rr]
               + acc[i][2][rr] * acc[i][2][rr] + acc[i][3][rr] * acc[i][3][rr];
#pragma unroll
      for (int d = 1; d < 16; d <<= 1) {
        s  += __shfl_xor(s, d, 64);
        sq += __shfl_xor(sq, d, 64);
      }
      if (r16 == 0) {
        const int rowl = wm + 16 * i + q4 * 4 + rr;
        redsum[w >> 1][rowl] = s;
        redsq[w >> 1][rowl]  = sq;
      }
    }
  __syncthreads();

  float mus[4][4], rstds[4][4];
#pragma unroll
  for (int i = 0; i < 4; i++)
#pragma unroll
    for (int rr = 0; rr < 4; rr++) {
      const int rowl = wm + 16 * i + q4 * 4 + rr;
      const float s  = redsum[0][rowl] + redsum[1][rowl] + redsum[2][rowl] + redsum[3][rowl];
      const float sq = redsq[0][rowl] + redsq[1][rowl] + redsq[2][rowl] + redsq[3][rowl];
      const float mu = s * (1.0f / 256.0f);
      const float var = sq * (1.0f / 256.0f) - mu * mu;
      mus[i][rr] = mu;
      rstds[i][rr] = rsqrtf(var + 1e-5f);
    }

  // gq = (x-mu)*rstd*g + b, hi/lo split in registers
  float gwv[4], bbv[4];
#pragma unroll
  for (int j = 0; j < 4; j++) {
    const int col = wn + 16 * j + r16;
    gwv[j] = ldf(lng, col, isf);
    bbv[j] = ldf(lnb, col, isf);
  }
  bf16x4 hi4[4][4], lo4[4][4];
#pragma unroll
  for (int i = 0; i < 4; i++)
#pragma unroll
    for (int j = 0; j < 4; j++)
#pragma unroll
      for (int rr = 0; rr < 4; rr++) {
        const float gv = (acc[i][j][rr] - mus[i][rr]) * rstds[i][rr] * gwv[j] + bbv[j];
        const bf16_t hi = (bf16_t)gv;
        hi4[i][j][rr] = hi;
        lo4[i][j][rr] = (bf16_t)(gv - (float)hi);
      }

  // ---------------- phase 3: offs/attw GEMM (out 128x128) ----------------
  const int wm2 = wm;                 // (w&1)*64
  const int wn2 = (w >> 1) * 32;      // 0,32,64,96
  f32x4 acc2[4][2] = {};
  const int myk = w >> 1;             // wave's gq col-chunk

  for (int c4 = 0; c4 < 4; c4++) {
    const int kt = c4 * 64;
    if (myk == c4) {
#pragma unroll
      for (int i = 0; i < 4; i++)
#pragma unroll
        for (int j = 0; j < 4; j++)
#pragma unroll
          for (int rr = 0; rr < 4; rr++) {
            const int r_ = wm + 16 * i + q4 * 4 + rr;
            Ah[r_ * 64 + 16 * j + r16] = hi4[i][j][rr];
            Al[r_ * 64 + 16 * j + r16] = lo4[i][j][rr];
          }
    }
#pragma unroll
    for (int r = 0; r < 2; r++) {
      const int L = r * 512 + t;
      const int R = L >> 3, cc = (L & 7) * 8;
      stage16(Whg + (size_t)R * 256 + kt + cc, Wh + L * 8);
      stage16(Wlg + (size_t)R * 256 + kt + cc, Wl + L * 8);
    }
    __syncthreads();
#pragma unroll
    for (int ks = 0; ks < 64; ks += 32) {
      bf16x8 ah[4], al[4], bh[2], bl[2];
#pragma unroll
      for (int i = 0; i < 4; i++) {
        ah[i] = *(const bf16x8*)(Ah + (wm2 + 16 * i + r16) * 64 + ks + q4 * 8);
        al[i] = *(const bf16x8*)(Al + (wm2 + 16 * i + r16) * 64 + ks + q4 * 8);
      }
#pragma unroll
      for (int j = 0; j < 2; j++) {
        bh[j] = *(const bf16x8*)(Wh + (wn2 + 16 * j + r16) * 64 + ks + q4 * 8);
        bl[j] = *(const bf16x8*)(Wl + (wn2 + 16 * j + r16) * 64 + ks + q4 * 8);
      }
#pragma unroll
      for (int i = 0; i < 4; i++)
#pragma unroll
        for (int j = 0; j < 2; j++) {
          f32x4 a = acc2[i][j];
          a = __builtin_amdgcn_mfma_f32_16x16x32_bf16(al[i], bh[j], a, 0, 0, 0);
          a = __builtin_amdgcn_mfma_f32_16x16x32_bf16(ah[i], bl[j], a, 0, 0, 0);
          a = __builtin_amdgcn_mfma_f32_16x16x32_bf16(ah[i], bh[j], a, 0, 0, 0);
          acc2[i][j] = a;
        }
    }
    __syncthreads();
  }

  // packed ysamp epilogue (same remap as old gemm_offs)
#pragma unroll
  for (int j = 0; j < 2; j++) {
    const int col = wn2 + 16 * j + r16;
    const float bv = (float)bpad[col];
    const int live  = (col < 96) ? 1 : 0;
    const int moff  = (col < 64) ? (col >> 3) : ((col - 64) >> 2);
    const int inner = (col < 64) ? (col & 7) : (8 + (col & 3));
#pragma unroll
    for (int i = 0; i < 4; i++) {
      const int row0 = R0 + wm2 + 16 * i + q4 * 4;
#pragma unroll
      for (int rr = 0; rr < 4; rr++) {
        if (live) {
          const int row = row0 + rr;
          const int bq = row >> 13, q = row & 8191;
          Cout[(((size_t)(bq * 8 + moff) << 13) + q) * 16 + inner] = acc2[i][j][rr] + bv;
        }
      }
    }
  }
}

// ===================== deformable bilinear sampler =========================
__global__ __launch_bounds__(256) void sampler(
    const float* __restrict__ ys2, const void* __restrict__ refp,
    const bf16_t* __restrict__ vperm, bf16_t* __restrict__ outs,
    const void* __restrict__ qdet)
{
  const int isf = detect_isf(qdet);
  const int t = threadIdx.x;
  const int wg = blockIdx.x;
  const int bm  = (wg & 7) + ((wg >> 9) << 3);  // XCD = wg%8 = bm%8
  const int mid = (wg >> 3) & 63;
  const int qt  = mid >> 1;
  const int hf  = mid & 1;                      // channel half
  const int b = bm >> 3, m = bm & 7;
  const int qq = qt * 256 + t;
  const size_t row = (size_t)b * 8192 + qq;
  const float* y16 = ys2 + (((size_t)bm << 13) + qq) * 16;
  const float rx = ldf(refp, row * 2 + 0, isf);
  const float ry = ldf(refp, row * 2 + 1, isf);

  const float4 off01 = *(const float4*)(y16 + 0);
  const float4 off23 = *(const float4*)(y16 + 4);
  const float4 lg    = *(const float4*)(y16 + 8);

  const float mx = fmaxf(fmaxf(lg.x, lg.y), fmaxf(lg.z, lg.w));
  const float e0 = __expf(lg.x - mx), e1 = __expf(lg.y - mx);
  const float e2 = __expf(lg.z - mx), e3 = __expf(lg.w - mx);
  const float inv = 1.0f / (e0 + e1 + e2 + e3);
  const float aw[4] = {e0 * inv, e1 * inv, e2 * inv, e3 * inv};
  const float ox[4] = {off01.x, off01.z, off23.x, off23.z};
  const float oy[4] = {off01.y, off01.w, off23.y, off23.w};

  float acc[16];
#pragma unroll
  for (int ch = 0; ch < 16; ch++) acc[ch] = 0.0f;

  const bf16_t* vbase = vperm + (size_t)bm * (128 * 128 * 32) + hf * 16;

  for (int p = 0; p < 4; p++) {
    const float gx = (rx + ox[p]) * 128.0f - 0.5f;
    const float gy = (ry + oy[p]) * 128.0f - 0.5f;
    const float x0f = floorf(gx), y0f = floorf(gy);
    const int x0 = (int)x0f, y0i = (int)y0f;
    const float wx1 = gx - x0f, wx0 = 1.0f - wx1;
    const float wy1 = gy - y0f, wy0 = 1.0f - wy1;
    const float a = aw[p];
    for (int cy = 0; cy < 2; cy++) {
      const int yy = y0i + cy;
      if (yy < 0 || yy >= 128) continue;
      const float wy = cy ? wy1 : wy0;
      for (int cx = 0; cx < 2; cx++) {
        const int xx = x0 + cx;
        if (xx < 0 || xx >= 128) continue;
        const float wgt = a * wy * (cx ? wx1 : wx0);
        const bf16x8* src8 = (const bf16x8*)(vbase + ((size_t)yy * 128 + xx) * 32);
        const bf16x8 d0 = src8[0];
        const bf16x8 d1 = src8[1];
#pragma unroll
        for (int e = 0; e < 8; e++) {
          acc[e]     += wgt * (float)d0[e];
          acc[8 + e] += wgt * (float)d1[e];
        }
      }
    }
  }

  const size_t obase = (size_t)b * 8192;
#pragma unroll
  for (int ch = 0; ch < 16; ch++) {
    const int chg = hf * 16 + ch;
    const size_t orow = obase + (size_t)(chg * 8 + m) * 32 + qt;
    outs[orow * 256 + t] = (bf16_t)acc[ch];
  }
}

// ===========================================================================
extern "C" void kernel_launch(void* const* d_in, const int* in_sizes, int n_in,
                              void* d_out, int out_size, void* d_ws, size_t ws_size,
                              hipStream_t stream) {
  const void* query = d_in[0];
  const void* value = d_in[1];
  const void* refp  = d_in[2];
  const void* trajp = d_in[3];
  const void* in_w  = d_in[4];
  const void* in_b  = d_in[5];
  const void* mow   = d_in[6];
  const void* mob   = d_in[7];
  const void* lng   = d_in[8];
  const void* lnb   = d_in[9];
  const void* tw    = d_in[10];
  const void* tb    = d_in[11];
  const void* ow    = d_in[12];
  const void* ob    = d_in[13];
  const void* aww   = d_in[14];
  const void* awb   = d_in[15];
  const void* outw  = d_in[16];
  const void* outb  = d_in[17];

  char* base = (char*)d_ws;
  float*  ysamp = (float*)(base);
  bf16_t* qout  = (bf16_t*)(base + 16777216);
  bf16_t* ctx   = (bf16_t*)(base + 33554432);
  bf16_t* outs  = (bf16_t*)(base + 50331648);
  bf16_t* tf_ws = (bf16_t*)(base + 67108864);
  bf16_t* k_ws  = (bf16_t*)(base + 68157440);
  bf16_t* vt_g  = (bf16_t*)(base + 69206016);
  bf16_t* blob  = (bf16_t*)(base + 70254592);
  bf16_t* vperm = (bf16_t*)(base + 134217728);

  bf16_t* inw_bf  = blob;
  bf16_t* inb_bf  = blob + 196608;
  bf16_t* mow_bf  = blob + 197376;
  bf16_t* mob_bf  = blob + 262912;
  bf16_t* outw_bf = blob + 263168;
  bf16_t* outb_bf = blob + 328704;
  bf16_t* wph     = blob + 328960;
  bf16_t* wpl     = blob + 361728;
  bf16_t* bpad    = blob + 394496;

  prep_all<<<dim3(6594), dim3(256), 0, stream>>>(
      query, in_w, in_b, mow, mob, outw, outb, trajp, tw, tb,
      ow, aww, ob, awb, blob, tf_ws, wph, wpl, bpad, value, vperm);
  gemm_qkv<<<dim3(576), dim3(256), 0, stream>>>(
      query, inw_bf, inb_bf, qout,
      tf_ws, inw_bf + 65536, inb_bf + 256, k_ws, vt_g, CEXP, query);
  attn_kernel<<<dim3(16, 32), dim3(256), 0, stream>>>(qout, k_ws, vt_g, ctx);
  gemm_mlo<<<dim3(256), dim3(512), 0, stream>>>(
      ctx, mow_bf, mob_bf, query, lng, lnb, wph, wpl, bpad, ysamp);
  sampler<<<dim3(2048), dim3(256), 0, stream>>>(ysamp, refp, vperm, outs, query);
  gemm_async<<<dim3(256, 2), dim3(256), 0, stream>>>(
      outs, outw_bf, outb_bf, d_out, nullptr, 256, 256, 3, 1.0f, query);
}